// Round 1
// baseline (1822.760 us; speedup 1.0000x reference)
//
#include <hip/hip_runtime.h>
#include <math.h>

static constexpr int Bc = 4, Lc = 2048, DMc = 512, Hc = 8, Dc = 64, DFFc = 2048, Uc = 40;
static constexpr int NT = Bc * Lc; // 8192 tokens

__device__ __forceinline__ float wave_sum(float v) {
#pragma unroll
  for (int off = 32; off > 0; off >>= 1) v += __shfl_xor(v, off);
  return v;
}

// ---------------------------------------------------------------------------
// Generic 64x64-tile f32 GEMM.
//   WT=false: C[m,n] = sum_k A[m,k] * W[k,n] + bias[n]
//   WT=true : C[m,n] = sum_k A[m,k] * W[n,k] + bias[n]
// MODE 0: plain store. MODE 1: relu store.
// MODE 2: scatter into (B,H,L,D) layout; optionally also (B,H,D,L) via C2.
// ---------------------------------------------------------------------------
template <bool WT, int MODE>
__global__ __launch_bounds__(256) void gemm64(
    const float* __restrict__ A, const float* __restrict__ W,
    const float* __restrict__ bias, float* __restrict__ C,
    float* __restrict__ C2, int M, int N, int K) {
  __shared__ float As[64][17];
  __shared__ float Ws[16][68];
  const int tid = threadIdx.x;
  const int m0 = blockIdx.y << 6, n0 = blockIdx.x << 6;
  const int tx = tid & 15, ty = tid >> 4;
  const int ar = tid >> 2, ac = (tid & 3) << 2;
  float acc[4][4] = {};
  for (int k0 = 0; k0 < K; k0 += 16) {
    float4 a4 = *reinterpret_cast<const float4*>(&A[(size_t)(m0 + ar) * K + k0 + ac]);
    As[ar][ac + 0] = a4.x; As[ar][ac + 1] = a4.y;
    As[ar][ac + 2] = a4.z; As[ar][ac + 3] = a4.w;
    if (!WT) {
      const int wr = tid >> 4, wc = (tid & 15) << 2;
      float4 w4 = *reinterpret_cast<const float4*>(&W[(size_t)(k0 + wr) * N + n0 + wc]);
      Ws[wr][wc + 0] = w4.x; Ws[wr][wc + 1] = w4.y;
      Ws[wr][wc + 2] = w4.z; Ws[wr][wc + 3] = w4.w;
    } else {
      const int wn = tid >> 2, wk = (tid & 3) << 2;
      float4 w4 = *reinterpret_cast<const float4*>(&W[(size_t)(n0 + wn) * K + k0 + wk]);
      Ws[wk + 0][wn] = w4.x; Ws[wk + 1][wn] = w4.y;
      Ws[wk + 2][wn] = w4.z; Ws[wk + 3][wn] = w4.w;
    }
    __syncthreads();
#pragma unroll
    for (int kk = 0; kk < 16; ++kk) {
      float a[4], b[4];
#pragma unroll
      for (int i = 0; i < 4; ++i) a[i] = As[(ty << 2) + i][kk];
#pragma unroll
      for (int j = 0; j < 4; ++j) b[j] = Ws[kk][(tx << 2) + j];
#pragma unroll
      for (int i = 0; i < 4; ++i)
#pragma unroll
        for (int j = 0; j < 4; ++j) acc[i][j] += a[i] * b[j];
    }
    __syncthreads();
  }
#pragma unroll
  for (int i = 0; i < 4; ++i) {
    int m = m0 + (ty << 2) + i;
#pragma unroll
    for (int j = 0; j < 4; ++j) {
      int n = n0 + (tx << 2) + j;
      float v = acc[i][j] + bias[n];
      if (MODE == 0) {
        C[(size_t)m * N + n] = v;
      } else if (MODE == 1) {
        C[(size_t)m * N + n] = fmaxf(v, 0.f);
      } else {
        int b = m >> 11, l = m & (Lc - 1);
        int h = n >> 6, d = n & 63;
        C[(size_t)((((b << 3) + h) * Lc + l) << 6) + d] = v;
        if (C2) C2[(size_t)((((b << 3) + h) << 6) + d) * Lc + l] = v;
      }
    }
  }
}

// M[b,h,l] = max_u(q.k_su) - mean_u(q.k_su); one wave per (b,h,l)
__global__ __launch_bounds__(256) void compute_M_kernel(
    const float* __restrict__ Q, const float* __restrict__ K,
    const int* __restrict__ sidx, float* __restrict__ Mout) {
  int gw = (blockIdx.x * blockDim.x + threadIdx.x) >> 6;  // (b*H+h)*L + l
  int lane = threadIdx.x & 63;
  int bh = gw >> 11, l = gw & (Lc - 1);
  float qd = Q[((size_t)gw << 6) + lane];
  float mx = -1e30f, sm = 0.f;
  for (int u = 0; u < Uc; ++u) {
    int idx = sidx[l * Uc + u];
    float kd = K[((size_t)((bh << 11) + idx) << 6) + lane];
    float s = wave_sum(qd * kd);
    mx = fmaxf(mx, s);
    sm += s;
  }
  if (lane == 0) Mout[gw] = mx - sm * (1.f / Uc);
}

// Exact stable top-k via rank counting (descending, ties -> lower index).
__global__ __launch_bounds__(256) void topk_kernel(const float* __restrict__ Min,
                                                   int* __restrict__ Mtop) {
  __shared__ float sm[Lc];
  int bh = blockIdx.x, tid = threadIdx.x;
  for (int i = tid; i < Lc; i += 256) sm[i] = Min[bh * Lc + i];
  __syncthreads();
  float myv[8]; int rank[8];
#pragma unroll
  for (int t = 0; t < 8; ++t) { myv[t] = sm[tid + (t << 8)]; rank[t] = 0; }
  for (int j = 0; j < Lc; ++j) {
    float w = sm[j];
#pragma unroll
    for (int t = 0; t < 8; ++t) {
      int i = tid + (t << 8);
      if (w > myv[t] || (w == myv[t] && j < i)) rank[t]++;
    }
  }
#pragma unroll
  for (int t = 0; t < 8; ++t)
    if (rank[t] < Uc) Mtop[bh * Uc + rank[t]] = tid + (t << 8);
}

// Full attention row for each selected query; one block per (b,h,u).
__global__ __launch_bounds__(256) void attn_kernel(
    const float* __restrict__ Q, const float* __restrict__ Kt,
    const float* __restrict__ V, const int* __restrict__ Mtop,
    float* __restrict__ ctx_top) {
  __shared__ float s[Lc];
  __shared__ float qs[Dc];
  __shared__ float red[4];
  __shared__ float ctxred[4][Dc];
  int bhu = blockIdx.x;
  int bh = bhu / Uc;
  int tid = threadIdx.x;
  int lsel = Mtop[bhu];
  if (tid < Dc) qs[tid] = Q[((size_t)(bh * Lc + lsel) << 6) + tid];
  __syncthreads();
  float lmax = -1e30f;
  for (int l = tid; l < Lc; l += 256) {
    float accv = 0.f;
#pragma unroll 8
    for (int d = 0; d < Dc; ++d)
      accv += qs[d] * Kt[(size_t)((bh << 6) + d) * Lc + l];
    accv *= 0.125f;  // 1/sqrt(64)
    s[l] = accv;
    lmax = fmaxf(lmax, accv);
  }
#pragma unroll
  for (int off = 32; off > 0; off >>= 1) lmax = fmaxf(lmax, __shfl_xor(lmax, off));
  if ((tid & 63) == 0) red[tid >> 6] = lmax;
  __syncthreads();
  float gmax = fmaxf(fmaxf(red[0], red[1]), fmaxf(red[2], red[3]));
  __syncthreads();
  float lsum = 0.f;
  for (int l = tid; l < Lc; l += 256) {
    float p = expf(s[l] - gmax);
    s[l] = p;
    lsum += p;
  }
  lsum = wave_sum(lsum);
  if ((tid & 63) == 0) red[tid >> 6] = lsum;
  __syncthreads();
  float gsum = red[0] + red[1] + red[2] + red[3];
  int w = tid >> 6, lane = tid & 63;
  float accd = 0.f;
  int lbase = w << 9;
  for (int l = lbase; l < lbase + 512; ++l)
    accd += s[l] * V[((size_t)(bh * Lc + l) << 6) + lane];
  ctxred[w][lane] = accd;
  __syncthreads();
  if (w == 0) {
    float tot = ctxred[0][lane] + ctxred[1][lane] + ctxred[2][lane] + ctxred[3][lane];
    ctx_top[(bhu << 6) + lane] = tot / gsum;
  }
}

__global__ __launch_bounds__(64) void vmean_kernel(const float* __restrict__ V,
                                                   float* __restrict__ vmean) {
  int blk = blockIdx.x;  // B*H*8
  int bh = blk >> 3, c = blk & 7;
  int lane = threadIdx.x;
  float sm = 0.f;
  int lbase = c << 8;
  for (int l = lbase; l < lbase + 256; ++l)
    sm += V[((size_t)(bh * Lc + l) << 6) + lane];
  atomicAdd(&vmean[(bh << 6) + lane], sm * (1.f / Lc));
}

// context[b,l,h*64+d] = vmean[b*512 + (h*64+d)]
__global__ __launch_bounds__(256) void build_ctx_kernel(const float* __restrict__ vmean,
                                                        float* __restrict__ ctx) {
  int idx = blockIdx.x * 256 + threadIdx.x;
  ctx[idx] = vmean[((idx >> 20) << 9) + (idx & 511)];
}

__global__ __launch_bounds__(64) void scatter_kernel(const float* __restrict__ ctop,
                                                     const int* __restrict__ Mtop,
                                                     float* __restrict__ ctx) {
  int bhu = blockIdx.x, d = threadIdx.x;
  int bh = bhu / Uc;
  int b = bh >> 3, h = bh & 7;
  int lsel = Mtop[bhu];
  ctx[(size_t)(b * Lc + lsel) * DMc + (h << 6) + d] = ctop[(bhu << 6) + d];
}

// out = LayerNorm(resid + yin) * g + b   (in-place safe when out==yin)
__global__ __launch_bounds__(256) void add_ln_kernel(
    const float* __restrict__ resid, const float* __restrict__ yin,
    const float* __restrict__ g, const float* __restrict__ bbias,
    float* __restrict__ out) {
  __shared__ float vals[DMc];
  __shared__ float red[4];
  int row = blockIdx.x, tid = threadIdx.x;
  size_t base = (size_t)row * DMc;
  float lsum = 0.f;
  for (int c = tid; c < DMc; c += 256) {
    float t = resid[base + c] + yin[base + c];
    vals[c] = t;
    lsum += t;
  }
  lsum = wave_sum(lsum);
  if ((tid & 63) == 0) red[tid >> 6] = lsum;
  __syncthreads();
  float mean = (red[0] + red[1] + red[2] + red[3]) * (1.f / DMc);
  __syncthreads();
  float lv = 0.f;
  for (int c = tid; c < DMc; c += 256) {
    float dv = vals[c] - mean;
    lv += dv * dv;
  }
  lv = wave_sum(lv);
  if ((tid & 63) == 0) red[tid >> 6] = lv;
  __syncthreads();
  float inv = rsqrtf((red[0] + red[1] + red[2] + red[3]) * (1.f / DMc) + 1e-5f);
  for (int c = tid; c < DMc; c += 256)
    out[base + c] = (vals[c] - mean) * inv * g[c] + bbias[c];
}

extern "C" void kernel_launch(void* const* d_in, const int* in_sizes, int n_in,
                              void* d_out, int out_size, void* d_ws, size_t ws_size,
                              hipStream_t stream) {
  (void)in_sizes; (void)n_in; (void)out_size; (void)ws_size;
  const float* x   = (const float*)d_in[0];
  const float* Wq  = (const float*)d_in[1];
  const float* bq  = (const float*)d_in[2];
  const float* Wk  = (const float*)d_in[3];
  const float* bk  = (const float*)d_in[4];
  const float* Wv  = (const float*)d_in[5];
  const float* bv  = (const float*)d_in[6];
  const float* Wo  = (const float*)d_in[7];
  const float* bo  = (const float*)d_in[8];
  const float* Wc1 = (const float*)d_in[9];
  const float* bc1 = (const float*)d_in[10];
  const float* Wc2 = (const float*)d_in[11];
  const float* bc2 = (const float*)d_in[12];
  const float* g1  = (const float*)d_in[13];
  const float* b1  = (const float*)d_in[14];
  const float* g2  = (const float*)d_in[15];
  const float* b2  = (const float*)d_in[16];
  const int* sidx  = (const int*)d_in[17];
  float* out = (float*)d_out;

  float* ws    = (float*)d_ws;
  float* Qb    = ws;              // 4,194,304 f32 (B,H,L,D)
  float* Kb    = ws + 4194304;    // (B,H,L,D)
  float* Vb    = ws + 8388608;    // (B,H,L,D)
  float* Ktb   = ws + 12582912;   // (B,H,D,L)
  float* CTX   = ws + 16777216;   // (B,L,DM)
  float* X1    = ws + 20971520;   // (B,L,DM)
  float* Mb    = ws + 25165824;   // 65536
  float* vmean = ws + 25231360;   // 2048
  float* ctop  = ws + 25233408;   // 81920
  int* Mtop    = (int*)(ws + 25315328);  // 1280
  float* Yb    = ws;              // FFN intermediate aliases dead Q/K/V/Kt (64MB)

  dim3 blk(256);
  gemm64<false, 2><<<dim3(8, 128), blk, 0, stream>>>(x, Wq, bq, Qb, nullptr, NT, DMc, DMc);
  gemm64<false, 2><<<dim3(8, 128), blk, 0, stream>>>(x, Wk, bk, Kb, Ktb, NT, DMc, DMc);
  gemm64<false, 2><<<dim3(8, 128), blk, 0, stream>>>(x, Wv, bv, Vb, nullptr, NT, DMc, DMc);
  compute_M_kernel<<<16384, blk, 0, stream>>>(Qb, Kb, sidx, Mb);
  topk_kernel<<<Bc * Hc, blk, 0, stream>>>(Mb, Mtop);
  attn_kernel<<<Bc * Hc * Uc, blk, 0, stream>>>(Qb, Ktb, Vb, Mtop, ctop);
  hipMemsetAsync(vmean, 0, Bc * Hc * Dc * sizeof(float), stream);
  vmean_kernel<<<Bc * Hc * 8, dim3(64), 0, stream>>>(Vb, vmean);
  build_ctx_kernel<<<16384, blk, 0, stream>>>(vmean, CTX);
  scatter_kernel<<<Bc * Hc * Uc, dim3(64), 0, stream>>>(ctop, Mtop, CTX);
  gemm64<false, 0><<<dim3(8, 128), blk, 0, stream>>>(CTX, Wo, bo, out, nullptr, NT, DMc, DMc);
  add_ln_kernel<<<NT, blk, 0, stream>>>(x, out, g1, b1, X1);
  gemm64<true, 1><<<dim3(32, 128), blk, 0, stream>>>(X1, Wc1, bc1, Yb, nullptr, NT, DFFc, DMc);
  gemm64<true, 0><<<dim3(8, 128), blk, 0, stream>>>(Yb, Wc2, bc2, out, nullptr, NT, DMc, DFFc);
  add_ln_kernel<<<NT, blk, 0, stream>>>(X1, out, g2, b2, out);
}

// Round 4
// 570.751 us; speedup vs baseline: 3.1936x; 3.1936x over previous
//
#include <hip/hip_runtime.h>
#include <math.h>

static constexpr int Bc = 4, Lc = 2048, DMc = 512, Hc = 8, Dc = 64, DFFc = 2048, Uc = 40;
static constexpr int NT = Bc * Lc; // 8192 tokens

typedef __attribute__((ext_vector_type(4))) float f32x4;
typedef __attribute__((ext_vector_type(8))) short bf16x8;
typedef unsigned short ushort_t;

__device__ __forceinline__ float wave_sum(float v) {
#pragma unroll
  for (int off = 32; off > 0; off >>= 1) v += __shfl_xor(v, off);
  return v;
}

__device__ __forceinline__ ushort_t f2bf(float f) {
  union { float f; unsigned int u; } c{f};
  unsigned int u = c.u + 0x7fff + ((c.u >> 16) & 1);
  return (ushort_t)(u >> 16);
}

__device__ __forceinline__ float bf2f(ushort_t b) {
  union { unsigned int u; float f; } c{(unsigned int)b << 16};
  return c.f;
}

__device__ __forceinline__ void gload16(const ushort_t* g, ushort_t* l) {
  __builtin_amdgcn_global_load_lds(
      (const __attribute__((address_space(1))) unsigned int*)g,
      (__attribute__((address_space(3))) unsigned int*)l, 16, 0, 0);
}

// ---------------------------------------------------------------------------
// bf16 MFMA GEMM, 128x128 tile, BK=32, 4 waves, m97 2-barrier structure.
// A: [M][K] bf16 row-major.  Bt: [N][K] bf16 (output-major == B transposed).
// MODE 0: Cf[m][n] = A@B + bias (f32)
// MODE 1: Cb[m][n] = bf16(relu(A@B + bias))
// MODE 2: QKV scatter (N=1536): f32 Q/K/V (B,H,L,D) + Kt (B,H,D,L)
// ---------------------------------------------------------------------------
template <int MODE>
__global__ __launch_bounds__(256) void gemm_mfma(
    const ushort_t* __restrict__ A, const ushort_t* __restrict__ Bt,
    const float* __restrict__ bias, float* __restrict__ Cf,
    ushort_t* __restrict__ Cb, float* __restrict__ Qo, float* __restrict__ Ko,
    float* __restrict__ Vo, float* __restrict__ Kt, int M, int N, int K) {
  __shared__ __align__(16) ushort_t As[128 * 32];
  __shared__ __align__(16) ushort_t Bs[128 * 32];
  const int tid = threadIdx.x;
  const int lane = tid & 63, wave = tid >> 6;
  const int m0 = blockIdx.y << 7, n0 = blockIdx.x << 7;
  const int wm = ((wave >> 1) << 6), wn = ((wave & 1) << 6);
  f32x4 acc[4][4] = {};
  const ushort_t* aSrc = A + (size_t)(m0 + (tid >> 2)) * K + ((tid & 3) << 3);
  const ushort_t* bSrc = Bt + (size_t)(n0 + (tid >> 2)) * K + ((tid & 3) << 3);
  ushort_t* aDst = As + wave * 512;  // wave-uniform LDS base; HW adds lane*16B
  ushort_t* bDst = Bs + wave * 512;
  const size_t aHalf = (size_t)64 * K, bHalf = (size_t)64 * K;
  for (int k0 = 0; k0 < K; k0 += 32) {
    gload16(aSrc + k0, aDst);
    gload16(aSrc + aHalf + k0, aDst + 2048);
    gload16(bSrc + k0, bDst);
    gload16(bSrc + bHalf + k0, bDst + 2048);
    __syncthreads();  // compiler drains vmcnt before s_barrier -> data ready
    bf16x8 af[4], bfr[4];
    const int fr = lane & 15, ko = (lane >> 4) << 3;
#pragma unroll
    for (int i = 0; i < 4; ++i) {
      af[i] = *reinterpret_cast<const bf16x8*>(&As[(wm + i * 16 + fr) * 32 + ko]);
      bfr[i] = *reinterpret_cast<const bf16x8*>(&Bs[(wn + i * 16 + fr) * 32 + ko]);
    }
#pragma unroll
    for (int i = 0; i < 4; ++i)
#pragma unroll
      for (int j = 0; j < 4; ++j)
        acc[i][j] = __builtin_amdgcn_mfma_f32_16x16x32_bf16(af[i], bfr[j], acc[i][j], 0, 0, 0);
    __syncthreads();
  }
  const int cr = (lane >> 4) << 2, cc = lane & 15;
#pragma unroll
  for (int j = 0; j < 4; ++j) {
    const int col = n0 + wn + j * 16 + cc;
    const float bsv = bias[col];
#pragma unroll
    for (int i = 0; i < 4; ++i) {
#pragma unroll
      for (int r = 0; r < 4; ++r) {
        const int row = m0 + wm + i * 16 + cr + r;
        float v = acc[i][j][r] + bsv;
        if (MODE == 0) {
          Cf[(size_t)row * N + col] = v;
        } else if (MODE == 1) {
          Cb[(size_t)row * N + col] = f2bf(fmaxf(v, 0.f));
        } else {
          const int which = col >> 9, h = (col >> 6) & 7, d = col & 63;
          const int b = row >> 11, l = row & (Lc - 1);
          const size_t o = ((size_t)(((b << 3) + h) << 11) + l) * 64 + d;
          float* dst = which == 0 ? Qo : (which == 1 ? Ko : Vo);
          dst[o] = v;
          if (which == 1)
            Kt[((size_t)(((b << 3) + h) << 6) + d) * Lc + l] = v;
        }
      }
    }
  }
}

// f32 -> bf16 elementwise (n multiple of 1024; grid = n/1024)
__global__ __launch_bounds__(256) void conv_bf16(const float* __restrict__ in,
                                                 ushort_t* __restrict__ out) {
  int i = blockIdx.x * 256 + threadIdx.x;
  float4 v = *reinterpret_cast<const float4*>(&in[(size_t)i * 4]);
  ushort4 o;
  o.x = f2bf(v.x); o.y = f2bf(v.y); o.z = f2bf(v.z); o.w = f2bf(v.w);
  *reinterpret_cast<ushort4*>(&out[(size_t)i * 4]) = o;
}

// transpose-convert: in f32 [R][C] -> out bf16 rows [rowOff + c][r], row stride R
__global__ __launch_bounds__(256) void tconv(const float* __restrict__ in,
                                             ushort_t* __restrict__ out,
                                             int R, int C, int rowOff) {
  __shared__ float t[32][33];
  const int r0 = blockIdx.y << 5, c0 = blockIdx.x << 5;
  const int tr = threadIdx.x >> 5, tc = threadIdx.x & 31;
#pragma unroll
  for (int p = 0; p < 4; ++p)
    t[tr + p * 8][tc] = in[(size_t)(r0 + tr + p * 8) * C + c0 + tc];
  __syncthreads();
#pragma unroll
  for (int p = 0; p < 4; ++p)
    out[(size_t)(rowOff + c0 + tr + p * 8) * R + r0 + tc] = f2bf(t[tc][tr + p * 8]);
}

__global__ __launch_bounds__(256) void concat_bias(const float* __restrict__ bq,
                                                   const float* __restrict__ bk,
                                                   const float* __restrict__ bv,
                                                   float* __restrict__ o) {
  int i = blockIdx.x * 256 + threadIdx.x;
  o[i] = i < 512 ? bq[i] : (i < 1024 ? bk[i - 512] : bv[i - 1024]);
}

// M[b,h,l] = max_u(q.k_su) - mean_u(q.k_su); one wave per (b,h,l)
__global__ __launch_bounds__(256) void compute_M_kernel(
    const float* __restrict__ Q, const float* __restrict__ K,
    const int* __restrict__ sidx, float* __restrict__ Mout) {
  int gw = (blockIdx.x * blockDim.x + threadIdx.x) >> 6;  // (b*H+h)*L + l
  int lane = threadIdx.x & 63;
  int bh = gw >> 11, l = gw & (Lc - 1);
  float qd = Q[((size_t)gw << 6) + lane];
  float mx = -1e30f, sm = 0.f;
  for (int u = 0; u < Uc; ++u) {
    int idx = sidx[l * Uc + u];
    float kd = K[((size_t)((bh << 11) + idx) << 6) + lane];
    float s = wave_sum(qd * kd);
    mx = fmaxf(mx, s);
    sm += s;
  }
  if (lane == 0) Mout[gw] = mx - sm * (1.f / Uc);
}

// Exact stable top-k via rank counting; grid = 32 bh * 8 chunks, 1 cand/thread.
__global__ __launch_bounds__(256) void topk_kernel(const float* __restrict__ Min,
                                                   int* __restrict__ Mtop) {
  __shared__ float sm[Lc];
  const int bh = blockIdx.x >> 3, chunk = blockIdx.x & 7;
  const int tid = threadIdx.x;
  for (int i = tid; i < Lc; i += 256) sm[i] = Min[bh * Lc + i];
  __syncthreads();
  const int cand = (chunk << 8) + tid;
  const float mv = sm[cand];
  int rank = 0;
  for (int j = 0; j < Lc; j += 4) {
    float4 w4 = *reinterpret_cast<const float4*>(&sm[j]);
    rank += (w4.x > mv || (w4.x == mv && (j + 0) < cand));
    rank += (w4.y > mv || (w4.y == mv && (j + 1) < cand));
    rank += (w4.z > mv || (w4.z == mv && (j + 2) < cand));
    rank += (w4.w > mv || (w4.w == mv && (j + 3) < cand));
  }
  if (rank < Uc) Mtop[bh * Uc + rank] = cand;
}

// Full attention row for each selected query; one block per (b,h,u).
__global__ __launch_bounds__(256) void attn_kernel(
    const float* __restrict__ Q, const float* __restrict__ Kt,
    const float* __restrict__ V, const int* __restrict__ Mtop,
    float* __restrict__ ctx_top) {
  __shared__ float s[Lc];
  __shared__ float qs[Dc];
  __shared__ float red[4];
  __shared__ float ctxred[4][Dc];
  int bhu = blockIdx.x;
  int bh = bhu / Uc;
  int tid = threadIdx.x;
  int lsel = Mtop[bhu];
  if (tid < Dc) qs[tid] = Q[((size_t)(bh * Lc + lsel) << 6) + tid];
  __syncthreads();
  float lmax = -1e30f;
  for (int l = tid; l < Lc; l += 256) {
    float accv = 0.f;
#pragma unroll 8
    for (int d = 0; d < Dc; ++d)
      accv += qs[d] * Kt[(size_t)((bh << 6) + d) * Lc + l];
    accv *= 0.125f;  // 1/sqrt(64)
    s[l] = accv;
    lmax = fmaxf(lmax, accv);
  }
#pragma unroll
  for (int off = 32; off > 0; off >>= 1) lmax = fmaxf(lmax, __shfl_xor(lmax, off));
  if ((tid & 63) == 0) red[tid >> 6] = lmax;
  __syncthreads();
  float gmax = fmaxf(fmaxf(red[0], red[1]), fmaxf(red[2], red[3]));
  __syncthreads();
  float lsum = 0.f;
  for (int l = tid; l < Lc; l += 256) {
    float p = expf(s[l] - gmax);
    s[l] = p;
    lsum += p;
  }
  lsum = wave_sum(lsum);
  if ((tid & 63) == 0) red[tid >> 6] = lsum;
  __syncthreads();
  float gsum = red[0] + red[1] + red[2] + red[3];
  int w = tid >> 6, lane = tid & 63;
  float accd = 0.f;
  int lbase = w << 9;
  for (int l = lbase; l < lbase + 512; ++l)
    accd += s[l] * V[((size_t)(bh * Lc + l) << 6) + lane];
  ctxred[w][lane] = accd;
  __syncthreads();
  if (w == 0) {
    float tot = ctxred[0][lane] + ctxred[1][lane] + ctxred[2][lane] + ctxred[3][lane];
    ctx_top[(bhu << 6) + lane] = tot / gsum;
  }
}

__global__ __launch_bounds__(64) void vmean_kernel(const float* __restrict__ V,
                                                   float* __restrict__ vmean) {
  int blk = blockIdx.x;  // B*H*8
  int bh = blk >> 3, c = blk & 7;
  int lane = threadIdx.x;
  float sm = 0.f;
  int lbase = c << 8;
  for (int l = lbase; l < lbase + 256; ++l)
    sm += V[((size_t)(bh * Lc + l) << 6) + lane];
  atomicAdd(&vmean[(bh << 6) + lane], sm * (1.f / Lc));
}

// ctxb[b,l,h*64+d] = bf16(vmean[b*512 + (h*64+d)])
__global__ __launch_bounds__(256) void build_ctx_kernel(const float* __restrict__ vmean,
                                                        ushort_t* __restrict__ ctxb) {
  int idx = blockIdx.x * 256 + threadIdx.x;
  ctxb[idx] = f2bf(vmean[((idx >> 20) << 9) + (idx & 511)]);
}

__global__ __launch_bounds__(64) void scatter_kernel(const float* __restrict__ ctop,
                                                     const int* __restrict__ Mtop,
                                                     ushort_t* __restrict__ ctxb) {
  int bhu = blockIdx.x, d = threadIdx.x;
  int bh = bhu / Uc;
  int b = bh >> 3, h = bh & 7;
  int lsel = Mtop[bhu];
  ctxb[(size_t)(b * Lc + lsel) * DMc + (h << 6) + d] = f2bf(ctop[(bhu << 6) + d]);
}

// out = LayerNorm(resid + yin) * g + b ; optional bf16 copy. In-place safe.
__global__ __launch_bounds__(256) void add_ln_kernel(
    const float* __restrict__ resid, const float* __restrict__ yin,
    const float* __restrict__ g, const float* __restrict__ bbias,
    float* __restrict__ out, ushort_t* __restrict__ outb) {
  __shared__ float vals[DMc];
  __shared__ float red[4];
  int row = blockIdx.x, tid = threadIdx.x;
  size_t base = (size_t)row * DMc;
  float lsum = 0.f;
  for (int c = tid; c < DMc; c += 256) {
    float t = resid[base + c] + yin[base + c];
    vals[c] = t;
    lsum += t;
  }
  lsum = wave_sum(lsum);
  if ((tid & 63) == 0) red[tid >> 6] = lsum;
  __syncthreads();
  float mean = (red[0] + red[1] + red[2] + red[3]) * (1.f / DMc);
  __syncthreads();
  float lv = 0.f;
  for (int c = tid; c < DMc; c += 256) {
    float dv = vals[c] - mean;
    lv += dv * dv;
  }
  lv = wave_sum(lv);
  if ((tid & 63) == 0) red[tid >> 6] = lv;
  __syncthreads();
  float inv = rsqrtf((red[0] + red[1] + red[2] + red[3]) * (1.f / DMc) + 1e-5f);
  for (int c = tid; c < DMc; c += 256) {
    float o = (vals[c] - mean) * inv * g[c] + bbias[c];
    out[base + c] = o;
    if (outb) outb[base + c] = f2bf(o);
  }
}

extern "C" void kernel_launch(void* const* d_in, const int* in_sizes, int n_in,
                              void* d_out, int out_size, void* d_ws, size_t ws_size,
                              hipStream_t stream) {
  (void)in_sizes; (void)n_in; (void)out_size; (void)ws_size;
  const float* x   = (const float*)d_in[0];
  const float* Wq  = (const float*)d_in[1];
  const float* bq  = (const float*)d_in[2];
  const float* Wk  = (const float*)d_in[3];
  const float* bk  = (const float*)d_in[4];
  const float* Wv  = (const float*)d_in[5];
  const float* bv  = (const float*)d_in[6];
  const float* Wo  = (const float*)d_in[7];
  const float* bo  = (const float*)d_in[8];
  const float* Wc1 = (const float*)d_in[9];
  const float* bc1 = (const float*)d_in[10];
  const float* Wc2 = (const float*)d_in[11];
  const float* bc2 = (const float*)d_in[12];
  const float* g1  = (const float*)d_in[13];
  const float* b1  = (const float*)d_in[14];
  const float* g2  = (const float*)d_in[15];
  const float* b2  = (const float*)d_in[16];
  const int* sidx  = (const int*)d_in[17];
  float* out = (float*)d_out;

  float* ws = (float*)d_ws;
  // f32-word offsets
  float* Qb     = ws;                       // (B,H,L,D) 4M
  float* Kb     = ws + 4194304;             // 4M
  float* Vb     = ws + 8388608;             // 4M
  float* Ktb    = ws + 12582912;            // (B,H,D,L) 4M
  float* X1     = ws + 16777216;            // 4M
  ushort_t* xb   = (ushort_t*)(ws + 20971520);  // [8192][512] bf16 (2M words)
  ushort_t* Wqkvt= (ushort_t*)(ws + 23068672);  // [1536][512] bf16
  ushort_t* Wot  = (ushort_t*)(ws + 23461888);  // [512][512] bf16
  ushort_t* Wc1b = (ushort_t*)(ws + 23592960);  // [2048][512] bf16
  ushort_t* Wc2b = (ushort_t*)(ws + 24117248);  // [512][2048] bf16
  float* bqkv   = ws + 24641536;            // 1536
  float* Mb     = ws + 24643072;            // 65536
  float* vmean  = ws + 24708608;            // 2048
  float* ctop   = ws + 24710656;            // 81920
  int* Mtop     = (int*)(ws + 24792576);    // 1280
  // aliases (producer runs strictly after last consumer of the dead buffer)
  ushort_t* CTXb = (ushort_t*)Vb;           // bf16 [8192][512], after vmean
  ushort_t* X1b  = (ushort_t*)Ktb;          // bf16 [8192][512], after attn
  ushort_t* Yb   = (ushort_t*)Qb;           // bf16 [8192][2048] over Q+K, after attn

  dim3 blk(256);
  conv_bf16<<<4096, blk, 0, stream>>>(x, xb);
  tconv<<<dim3(16, 16), blk, 0, stream>>>(Wq, Wqkvt, 512, 512, 0);
  tconv<<<dim3(16, 16), blk, 0, stream>>>(Wk, Wqkvt, 512, 512, 512);
  tconv<<<dim3(16, 16), blk, 0, stream>>>(Wv, Wqkvt, 512, 512, 1024);
  tconv<<<dim3(16, 16), blk, 0, stream>>>(Wo, Wot, 512, 512, 0);
  conv_bf16<<<1024, blk, 0, stream>>>(Wc1, Wc1b);
  conv_bf16<<<1024, blk, 0, stream>>>(Wc2, Wc2b);
  concat_bias<<<6, blk, 0, stream>>>(bq, bk, bv, bqkv);

  gemm_mfma<2><<<dim3(12, 64), blk, 0, stream>>>(xb, Wqkvt, bqkv, nullptr, nullptr,
                                                 Qb, Kb, Vb, Ktb, NT, 1536, DMc);
  compute_M_kernel<<<16384, blk, 0, stream>>>(Qb, Kb, sidx, Mb);
  topk_kernel<<<256, blk, 0, stream>>>(Mb, Mtop);
  attn_kernel<<<Bc * Hc * Uc, blk, 0, stream>>>(Qb, Ktb, Vb, Mtop, ctop);
  hipMemsetAsync(vmean, 0, Bc * Hc * Dc * sizeof(float), stream);
  vmean_kernel<<<Bc * Hc * 8, dim3(64), 0, stream>>>(Vb, vmean);
  build_ctx_kernel<<<16384, blk, 0, stream>>>(vmean, CTXb);
  scatter_kernel<<<Bc * Hc * Uc, dim3(64), 0, stream>>>(ctop, Mtop, CTXb);

  gemm_mfma<0><<<dim3(4, 64), blk, 0, stream>>>(CTXb, Wot, bo, out, nullptr,
                                                nullptr, nullptr, nullptr, nullptr,
                                                NT, DMc, DMc);
  add_ln_kernel<<<NT, blk, 0, stream>>>(x, out, g1, b1, X1, X1b);
  gemm_mfma<1><<<dim3(16, 64), blk, 0, stream>>>(X1b, Wc1b, bc1, nullptr, Yb,
                                                 nullptr, nullptr, nullptr, nullptr,
                                                 NT, DFFc, DMc);
  gemm_mfma<0><<<dim3(4, 64), blk, 0, stream>>>(Yb, Wc2b, bc2, out, nullptr,
                                                nullptr, nullptr, nullptr, nullptr,
                                                NT, DMc, DFFc);
  add_ln_kernel<<<NT, blk, 0, stream>>>(X1, out, g2, b2, out, nullptr);
}

// Round 5
// 456.034 us; speedup vs baseline: 3.9970x; 1.2516x over previous
//
#include <hip/hip_runtime.h>
#include <math.h>

static constexpr int Bc = 4, Lc = 2048, DMc = 512, Hc = 8, Dc = 64, DFFc = 2048, Uc = 40;
static constexpr int NT = Bc * Lc; // 8192 tokens

typedef __attribute__((ext_vector_type(4))) float f32x4;
typedef __attribute__((ext_vector_type(8))) short bf16x8;
typedef unsigned short ushort_t;

__device__ __forceinline__ float wave_sum(float v) {
#pragma unroll
  for (int off = 32; off > 0; off >>= 1) v += __shfl_xor(v, off);
  return v;
}

__device__ __forceinline__ ushort_t f2bf(float f) {
  union { float f; unsigned int u; } c{f};
  unsigned int u = c.u + 0x7fff + ((c.u >> 16) & 1);
  return (ushort_t)(u >> 16);
}

__device__ __forceinline__ float bf2f(ushort_t b) {
  union { unsigned int u; float f; } c{(unsigned int)b << 16};
  return c.f;
}

__device__ __forceinline__ void gload16(const ushort_t* g, ushort_t* l) {
  __builtin_amdgcn_global_load_lds(
      (const __attribute__((address_space(1))) unsigned int*)g,
      (__attribute__((address_space(3))) unsigned int*)l, 16, 0, 0);
}

// ---------------------------------------------------------------------------
// bf16 MFMA GEMM, 128x128 tile, BK=32, 4 waves, m97 2-barrier structure.
// ---------------------------------------------------------------------------
template <int MODE>
__global__ __launch_bounds__(256) void gemm_mfma(
    const ushort_t* __restrict__ A, const ushort_t* __restrict__ Bt,
    const float* __restrict__ bias, float* __restrict__ Cf,
    ushort_t* __restrict__ Cb, float* __restrict__ Qo, float* __restrict__ Ko,
    float* __restrict__ Vo, float* __restrict__ Kt, int M, int N, int K) {
  __shared__ __align__(16) ushort_t As[128 * 32];
  __shared__ __align__(16) ushort_t Bs[128 * 32];
  const int tid = threadIdx.x;
  const int lane = tid & 63, wave = tid >> 6;
  const int m0 = blockIdx.y << 7, n0 = blockIdx.x << 7;
  const int wm = ((wave >> 1) << 6), wn = ((wave & 1) << 6);
  f32x4 acc[4][4] = {};
  const ushort_t* aSrc = A + (size_t)(m0 + (tid >> 2)) * K + ((tid & 3) << 3);
  const ushort_t* bSrc = Bt + (size_t)(n0 + (tid >> 2)) * K + ((tid & 3) << 3);
  ushort_t* aDst = As + wave * 512;  // wave-uniform LDS base; HW adds lane*16B
  ushort_t* bDst = Bs + wave * 512;
  const size_t aHalf = (size_t)64 * K, bHalf = (size_t)64 * K;
  for (int k0 = 0; k0 < K; k0 += 32) {
    gload16(aSrc + k0, aDst);
    gload16(aSrc + aHalf + k0, aDst + 2048);
    gload16(bSrc + k0, bDst);
    gload16(bSrc + bHalf + k0, bDst + 2048);
    __syncthreads();  // compiler drains vmcnt before s_barrier -> data ready
    bf16x8 af[4], bfr[4];
    const int fr = lane & 15, ko = (lane >> 4) << 3;
#pragma unroll
    for (int i = 0; i < 4; ++i) {
      af[i] = *reinterpret_cast<const bf16x8*>(&As[(wm + i * 16 + fr) * 32 + ko]);
      bfr[i] = *reinterpret_cast<const bf16x8*>(&Bs[(wn + i * 16 + fr) * 32 + ko]);
    }
#pragma unroll
    for (int i = 0; i < 4; ++i)
#pragma unroll
      for (int j = 0; j < 4; ++j)
        acc[i][j] = __builtin_amdgcn_mfma_f32_16x16x32_bf16(af[i], bfr[j], acc[i][j], 0, 0, 0);
    __syncthreads();
  }
  const int cr = (lane >> 4) << 2, cc = lane & 15;
#pragma unroll
  for (int j = 0; j < 4; ++j) {
    const int col = n0 + wn + j * 16 + cc;
    const float bsv = bias[col];
#pragma unroll
    for (int i = 0; i < 4; ++i) {
#pragma unroll
      for (int r = 0; r < 4; ++r) {
        const int row = m0 + wm + i * 16 + cr + r;
        float v = acc[i][j][r] + bsv;
        if (MODE == 0) {
          Cf[(size_t)row * N + col] = v;
        } else if (MODE == 1) {
          Cb[(size_t)row * N + col] = f2bf(fmaxf(v, 0.f));
        } else {
          const int which = col >> 9, h = (col >> 6) & 7, d = col & 63;
          const int b = row >> 11, l = row & (Lc - 1);
          const size_t o = ((size_t)(((b << 3) + h) << 11) + l) * 64 + d;
          float* dst = which == 0 ? Qo : (which == 1 ? Ko : Vo);
          dst[o] = v;
          if (which == 1)
            Kt[((size_t)(((b << 3) + h) << 6) + d) * Lc + l] = v;
        }
      }
    }
  }
}

// f32 -> bf16 elementwise (n multiple of 1024; grid = n/1024)
__global__ __launch_bounds__(256) void conv_bf16(const float* __restrict__ in,
                                                 ushort_t* __restrict__ out) {
  int i = blockIdx.x * 256 + threadIdx.x;
  float4 v = *reinterpret_cast<const float4*>(&in[(size_t)i * 4]);
  ushort4 o;
  o.x = f2bf(v.x); o.y = f2bf(v.y); o.z = f2bf(v.z); o.w = f2bf(v.w);
  *reinterpret_cast<ushort4*>(&out[(size_t)i * 4]) = o;
}

// transpose-convert: in f32 [R][C] -> out bf16 rows [rowOff + c][r], row stride R
__global__ __launch_bounds__(256) void tconv(const float* __restrict__ in,
                                             ushort_t* __restrict__ out,
                                             int R, int C, int rowOff) {
  __shared__ float t[32][33];
  const int r0 = blockIdx.y << 5, c0 = blockIdx.x << 5;
  const int tr = threadIdx.x >> 5, tc = threadIdx.x & 31;
#pragma unroll
  for (int p = 0; p < 4; ++p)
    t[tr + p * 8][tc] = in[(size_t)(r0 + tr + p * 8) * C + c0 + tc];
  __syncthreads();
#pragma unroll
  for (int p = 0; p < 4; ++p)
    out[(size_t)(rowOff + c0 + tr + p * 8) * R + r0 + tc] = f2bf(t[tc][tr + p * 8]);
}

__global__ __launch_bounds__(256) void concat_bias(const float* __restrict__ bq,
                                                   const float* __restrict__ bk,
                                                   const float* __restrict__ bv,
                                                   float* __restrict__ o) {
  int i = blockIdx.x * 256 + threadIdx.x;
  o[i] = i < 512 ? bq[i] : (i < 1024 ? bk[i - 512] : bv[i - 1024]);
}

// M[b,h,l] = max_u(q.k_su) - mean_u(q.k_su)
// 16-lane group per (b,h,l): lane holds float4 of q; per u: coalesced float4
// K load + 4 FMA + 4-step shfl reduce. unroll 4 -> 4 chains in flight.
__global__ __launch_bounds__(256) void compute_M_kernel(
    const float* __restrict__ Q, const float* __restrict__ K,
    const int* __restrict__ sidx, float* __restrict__ Mout) {
  const int tid = threadIdx.x;
  const int wave = tid >> 6, lane = tid & 63;
  const int g = lane >> 4, lg = lane & 15;
  const int gw = blockIdx.x * 16 + wave * 4 + g;  // (b*H+h)*L + l
  const int bh = gw >> 11, l = gw & (Lc - 1);
  const float4 q4 = *reinterpret_cast<const float4*>(&Q[((size_t)gw << 6) + (lg << 2)]);
  const float* Kbase = K + ((size_t)bh << 17);  // bh * L * D
  const int* sp = sidx + l * Uc;
  float mx = -1e30f, sm = 0.f;
#pragma unroll 4
  for (int u = 0; u < Uc; ++u) {
    const int idx = sp[u];
    const float4 k4 = *reinterpret_cast<const float4*>(&Kbase[((size_t)idx << 6) + (lg << 2)]);
    float d = q4.x * k4.x + q4.y * k4.y + q4.z * k4.z + q4.w * k4.w;
#pragma unroll
    for (int off = 8; off > 0; off >>= 1) d += __shfl_xor(d, off);
    mx = fmaxf(mx, d);
    sm += d;
  }
  if (lg == 0) Mout[gw] = mx - sm * (1.f / Uc);
}

// Exact stable top-k via rank counting; grid = 32 bh * 8 chunks, 1 cand/thread.
__global__ __launch_bounds__(256) void topk_kernel(const float* __restrict__ Min,
                                                   int* __restrict__ Mtop) {
  __shared__ float sm[Lc];
  const int bh = blockIdx.x >> 3, chunk = blockIdx.x & 7;
  const int tid = threadIdx.x;
  for (int i = tid; i < Lc; i += 256) sm[i] = Min[bh * Lc + i];
  __syncthreads();
  const int cand = (chunk << 8) + tid;
  const float mv = sm[cand];
  int rank = 0;
  for (int j = 0; j < Lc; j += 4) {
    float4 w4 = *reinterpret_cast<const float4*>(&sm[j]);
    rank += (w4.x > mv || (w4.x == mv && (j + 0) < cand));
    rank += (w4.y > mv || (w4.y == mv && (j + 1) < cand));
    rank += (w4.z > mv || (w4.z == mv && (j + 2) < cand));
    rank += (w4.w > mv || (w4.w == mv && (j + 3) < cand));
  }
  if (rank < Uc) Mtop[bh * Uc + rank] = cand;
}

// Full attention row for each selected query; one block per (b,h,u).
__global__ __launch_bounds__(256) void attn_kernel(
    const float* __restrict__ Q, const float* __restrict__ Kt,
    const float* __restrict__ V, const int* __restrict__ Mtop,
    float* __restrict__ ctx_top) {
  __shared__ float s[Lc];
  __shared__ float qs[Dc];
  __shared__ float red[4];
  __shared__ float ctxred[4][Dc];
  int bhu = blockIdx.x;
  int bh = bhu / Uc;
  int tid = threadIdx.x;
  int lsel = Mtop[bhu];
  if (tid < Dc) qs[tid] = Q[((size_t)(bh * Lc + lsel) << 6) + tid];
  __syncthreads();
  float lmax = -1e30f;
  for (int l = tid; l < Lc; l += 256) {
    float accv = 0.f;
#pragma unroll 8
    for (int d = 0; d < Dc; ++d)
      accv += qs[d] * Kt[(size_t)((bh << 6) + d) * Lc + l];
    accv *= 0.125f;  // 1/sqrt(64)
    s[l] = accv;
    lmax = fmaxf(lmax, accv);
  }
#pragma unroll
  for (int off = 32; off > 0; off >>= 1) lmax = fmaxf(lmax, __shfl_xor(lmax, off));
  if ((tid & 63) == 0) red[tid >> 6] = lmax;
  __syncthreads();
  float gmax = fmaxf(fmaxf(red[0], red[1]), fmaxf(red[2], red[3]));
  __syncthreads();
  float lsum = 0.f;
  for (int l = tid; l < Lc; l += 256) {
    float p = expf(s[l] - gmax);
    s[l] = p;
    lsum += p;
  }
  lsum = wave_sum(lsum);
  if ((tid & 63) == 0) red[tid >> 6] = lsum;
  __syncthreads();
  float gsum = red[0] + red[1] + red[2] + red[3];
  int w = tid >> 6, lane = tid & 63;
  float accd = 0.f;
  int lbase = w << 9;
  for (int l = lbase; l < lbase + 512; ++l)
    accd += s[l] * V[((size_t)(bh * Lc + l) << 6) + lane];
  ctxred[w][lane] = accd;
  __syncthreads();
  if (w == 0) {
    float tot = ctxred[0][lane] + ctxred[1][lane] + ctxred[2][lane] + ctxred[3][lane];
    ctx_top[(bhu << 6) + lane] = tot / gsum;
  }
}

__global__ __launch_bounds__(64) void vmean_kernel(const float* __restrict__ V,
                                                   float* __restrict__ vmean) {
  int blk = blockIdx.x;  // B*H*8
  int bh = blk >> 3, c = blk & 7;
  int lane = threadIdx.x;
  float sm = 0.f;
  int lbase = c << 8;
  for (int l = lbase; l < lbase + 256; ++l)
    sm += V[((size_t)(bh * Lc + l) << 6) + lane];
  atomicAdd(&vmean[(bh << 6) + lane], sm * (1.f / Lc));
}

// ctxb[b,l,h*64+d] = bf16(vmean[b*512 + (h*64+d)])
__global__ __launch_bounds__(256) void build_ctx_kernel(const float* __restrict__ vmean,
                                                        ushort_t* __restrict__ ctxb) {
  int idx = blockIdx.x * 256 + threadIdx.x;
  ctxb[idx] = f2bf(vmean[((idx >> 20) << 9) + (idx & 511)]);
}

__global__ __launch_bounds__(64) void scatter_kernel(const float* __restrict__ ctop,
                                                     const int* __restrict__ Mtop,
                                                     ushort_t* __restrict__ ctxb) {
  int bhu = blockIdx.x, d = threadIdx.x;
  int bh = bhu / Uc;
  int b = bh >> 3, h = bh & 7;
  int lsel = Mtop[bhu];
  ctxb[(size_t)(b * Lc + lsel) * DMc + (h << 6) + d] = f2bf(ctop[(bhu << 6) + d]);
}

// out = LayerNorm(resid + yin) * g + b ; optional bf16 copy. In-place safe.
__global__ __launch_bounds__(256) void add_ln_kernel(
    const float* __restrict__ resid, const float* __restrict__ yin,
    const float* __restrict__ g, const float* __restrict__ bbias,
    float* __restrict__ out, ushort_t* __restrict__ outb) {
  __shared__ float vals[DMc];
  __shared__ float red[4];
  int row = blockIdx.x, tid = threadIdx.x;
  size_t base = (size_t)row * DMc;
  float lsum = 0.f;
  for (int c = tid; c < DMc; c += 256) {
    float t = resid[base + c] + yin[base + c];
    vals[c] = t;
    lsum += t;
  }
  lsum = wave_sum(lsum);
  if ((tid & 63) == 0) red[tid >> 6] = lsum;
  __syncthreads();
  float mean = (red[0] + red[1] + red[2] + red[3]) * (1.f / DMc);
  __syncthreads();
  float lv = 0.f;
  for (int c = tid; c < DMc; c += 256) {
    float dv = vals[c] - mean;
    lv += dv * dv;
  }
  lv = wave_sum(lv);
  if ((tid & 63) == 0) red[tid >> 6] = lv;
  __syncthreads();
  float inv = rsqrtf((red[0] + red[1] + red[2] + red[3]) * (1.f / DMc) + 1e-5f);
  for (int c = tid; c < DMc; c += 256) {
    float o = (vals[c] - mean) * inv * g[c] + bbias[c];
    out[base + c] = o;
    if (outb) outb[base + c] = f2bf(o);
  }
}

extern "C" void kernel_launch(void* const* d_in, const int* in_sizes, int n_in,
                              void* d_out, int out_size, void* d_ws, size_t ws_size,
                              hipStream_t stream) {
  (void)in_sizes; (void)n_in; (void)out_size; (void)ws_size;
  const float* x   = (const float*)d_in[0];
  const float* Wq  = (const float*)d_in[1];
  const float* bq  = (const float*)d_in[2];
  const float* Wk  = (const float*)d_in[3];
  const float* bk  = (const float*)d_in[4];
  const float* Wv  = (const float*)d_in[5];
  const float* bv  = (const float*)d_in[6];
  const float* Wo  = (const float*)d_in[7];
  const float* bo  = (const float*)d_in[8];
  const float* Wc1 = (const float*)d_in[9];
  const float* bc1 = (const float*)d_in[10];
  const float* Wc2 = (const float*)d_in[11];
  const float* bc2 = (const float*)d_in[12];
  const float* g1  = (const float*)d_in[13];
  const float* b1  = (const float*)d_in[14];
  const float* g2  = (const float*)d_in[15];
  const float* b2  = (const float*)d_in[16];
  const int* sidx  = (const int*)d_in[17];
  float* out = (float*)d_out;

  float* ws = (float*)d_ws;
  // f32-word offsets
  float* Qb     = ws;                       // (B,H,L,D) 4M
  float* Kb     = ws + 4194304;             // 4M
  float* Vb     = ws + 8388608;             // 4M
  float* Ktb    = ws + 12582912;            // (B,H,D,L) 4M
  float* X1     = ws + 16777216;            // 4M
  ushort_t* xb   = (ushort_t*)(ws + 20971520);  // [8192][512] bf16 (2M words)
  ushort_t* Wqkvt= (ushort_t*)(ws + 23068672);  // [1536][512] bf16
  ushort_t* Wot  = (ushort_t*)(ws + 23461888);  // [512][512] bf16
  ushort_t* Wc1b = (ushort_t*)(ws + 23592960);  // [2048][512] bf16
  ushort_t* Wc2b = (ushort_t*)(ws + 24117248);  // [512][2048] bf16
  float* bqkv   = ws + 24641536;            // 1536
  float* Mb     = ws + 24643072;            // 65536
  float* vmean  = ws + 24708608;            // 2048
  float* ctop   = ws + 24710656;            // 81920
  int* Mtop     = (int*)(ws + 24792576);    // 1280
  // aliases (producer runs strictly after last consumer of the dead buffer)
  ushort_t* CTXb = (ushort_t*)Vb;           // bf16 [8192][512], after vmean
  ushort_t* X1b  = (ushort_t*)Ktb;          // bf16 [8192][512], after attn
  ushort_t* Yb   = (ushort_t*)Qb;           // bf16 [8192][2048] over Q+K, after attn

  dim3 blk(256);
  conv_bf16<<<4096, blk, 0, stream>>>(x, xb);
  tconv<<<dim3(16, 16), blk, 0, stream>>>(Wq, Wqkvt, 512, 512, 0);
  tconv<<<dim3(16, 16), blk, 0, stream>>>(Wk, Wqkvt, 512, 512, 512);
  tconv<<<dim3(16, 16), blk, 0, stream>>>(Wv, Wqkvt, 512, 512, 1024);
  tconv<<<dim3(16, 16), blk, 0, stream>>>(Wo, Wot, 512, 512, 0);
  conv_bf16<<<1024, blk, 0, stream>>>(Wc1, Wc1b);
  conv_bf16<<<1024, blk, 0, stream>>>(Wc2, Wc2b);
  concat_bias<<<6, blk, 0, stream>>>(bq, bk, bv, bqkv);

  gemm_mfma<2><<<dim3(12, 64), blk, 0, stream>>>(xb, Wqkvt, bqkv, nullptr, nullptr,
                                                 Qb, Kb, Vb, Ktb, NT, 1536, DMc);
  compute_M_kernel<<<4096, blk, 0, stream>>>(Qb, Kb, sidx, Mb);
  topk_kernel<<<256, blk, 0, stream>>>(Mb, Mtop);
  attn_kernel<<<Bc * Hc * Uc, blk, 0, stream>>>(Qb, Ktb, Vb, Mtop, ctop);
  hipMemsetAsync(vmean, 0, Bc * Hc * Dc * sizeof(float), stream);
  vmean_kernel<<<Bc * Hc * 8, dim3(64), 0, stream>>>(Vb, vmean);
  build_ctx_kernel<<<16384, blk, 0, stream>>>(vmean, CTXb);
  scatter_kernel<<<Bc * Hc * Uc, dim3(64), 0, stream>>>(ctop, Mtop, CTXb);

  gemm_mfma<0><<<dim3(4, 64), blk, 0, stream>>>(CTXb, Wot, bo, out, nullptr,
                                                nullptr, nullptr, nullptr, nullptr,
                                                NT, DMc, DMc);
  add_ln_kernel<<<NT, blk, 0, stream>>>(x, out, g1, b1, X1, X1b);
  gemm_mfma<1><<<dim3(16, 64), blk, 0, stream>>>(X1b, Wc1b, bc1, nullptr, Yb,
                                                 nullptr, nullptr, nullptr, nullptr,
                                                 NT, DFFc, DMc);
  gemm_mfma<0><<<dim3(4, 64), blk, 0, stream>>>(Yb, Wc2b, bc2, out, nullptr,
                                                nullptr, nullptr, nullptr, nullptr,
                                                NT, DMc, DFFc);
  add_ln_kernel<<<NT, blk, 0, stream>>>(X1, out, g2, b2, out, nullptr);
}

// Round 6
// 445.382 us; speedup vs baseline: 4.0926x; 1.0239x over previous
//
#include <hip/hip_runtime.h>
#include <math.h>

static constexpr int Bc = 4, Lc = 2048, DMc = 512, Hc = 8, Dc = 64, DFFc = 2048, Uc = 40;
static constexpr int NT = Bc * Lc; // 8192 tokens

typedef __attribute__((ext_vector_type(4))) float f32x4;
typedef __attribute__((ext_vector_type(8))) short bf16x8;
typedef unsigned short ushort_t;

__device__ __forceinline__ float wave_sum(float v) {
#pragma unroll
  for (int off = 32; off > 0; off >>= 1) v += __shfl_xor(v, off);
  return v;
}

__device__ __forceinline__ ushort_t f2bf(float f) {
  union { float f; unsigned int u; } c{f};
  unsigned int u = c.u + 0x7fff + ((c.u >> 16) & 1);
  return (ushort_t)(u >> 16);
}

__device__ __forceinline__ void gload16(const ushort_t* g, ushort_t* l) {
  __builtin_amdgcn_global_load_lds(
      (const __attribute__((address_space(1))) unsigned int*)g,
      (__attribute__((address_space(3))) unsigned int*)l, 16, 0, 0);
}

// ---------------------------------------------------------------------------
// bf16 MFMA GEMM, 128x128 tile, BK=32, 4 waves, m97 2-barrier structure.
// ---------------------------------------------------------------------------
template <int MODE>
__global__ __launch_bounds__(256) void gemm_mfma(
    const ushort_t* __restrict__ A, const ushort_t* __restrict__ Bt,
    const float* __restrict__ bias, float* __restrict__ Cf,
    ushort_t* __restrict__ Cb, float* __restrict__ Qo, float* __restrict__ Ko,
    float* __restrict__ Vo, float* __restrict__ Kt, int M, int N, int K) {
  __shared__ __align__(16) ushort_t As[128 * 32];
  __shared__ __align__(16) ushort_t Bs[128 * 32];
  const int tid = threadIdx.x;
  const int lane = tid & 63, wave = tid >> 6;
  const int m0 = blockIdx.y << 7, n0 = blockIdx.x << 7;
  const int wm = ((wave >> 1) << 6), wn = ((wave & 1) << 6);
  f32x4 acc[4][4] = {};
  const ushort_t* aSrc = A + (size_t)(m0 + (tid >> 2)) * K + ((tid & 3) << 3);
  const ushort_t* bSrc = Bt + (size_t)(n0 + (tid >> 2)) * K + ((tid & 3) << 3);
  ushort_t* aDst = As + wave * 512;  // wave-uniform LDS base; HW adds lane*16B
  ushort_t* bDst = Bs + wave * 512;
  const size_t aHalf = (size_t)64 * K, bHalf = (size_t)64 * K;
  for (int k0 = 0; k0 < K; k0 += 32) {
    gload16(aSrc + k0, aDst);
    gload16(aSrc + aHalf + k0, aDst + 2048);
    gload16(bSrc + k0, bDst);
    gload16(bSrc + bHalf + k0, bDst + 2048);
    __syncthreads();  // compiler drains vmcnt before s_barrier -> data ready
    bf16x8 af[4], bfr[4];
    const int fr = lane & 15, ko = (lane >> 4) << 3;
#pragma unroll
    for (int i = 0; i < 4; ++i) {
      af[i] = *reinterpret_cast<const bf16x8*>(&As[(wm + i * 16 + fr) * 32 + ko]);
      bfr[i] = *reinterpret_cast<const bf16x8*>(&Bs[(wn + i * 16 + fr) * 32 + ko]);
    }
#pragma unroll
    for (int i = 0; i < 4; ++i)
#pragma unroll
      for (int j = 0; j < 4; ++j)
        acc[i][j] = __builtin_amdgcn_mfma_f32_16x16x32_bf16(af[i], bfr[j], acc[i][j], 0, 0, 0);
    __syncthreads();
  }
  const int cr = (lane >> 4) << 2, cc = lane & 15;
#pragma unroll
  for (int j = 0; j < 4; ++j) {
    const int col = n0 + wn + j * 16 + cc;
    const float bsv = bias[col];
#pragma unroll
    for (int i = 0; i < 4; ++i) {
#pragma unroll
      for (int r = 0; r < 4; ++r) {
        const int row = m0 + wm + i * 16 + cr + r;
        float v = acc[i][j][r] + bsv;
        if (MODE == 0) {
          Cf[(size_t)row * N + col] = v;
        } else if (MODE == 1) {
          Cb[(size_t)row * N + col] = f2bf(fmaxf(v, 0.f));
        } else {
          const int which = col >> 9, h = (col >> 6) & 7, d = col & 63;
          const int b = row >> 11, l = row & (Lc - 1);
          const size_t o = ((size_t)(((b << 3) + h) << 11) + l) * 64 + d;
          float* dst = which == 0 ? Qo : (which == 1 ? Ko : Vo);
          dst[o] = v;
          if (which == 1 && Kt)
            Kt[((size_t)(((b << 3) + h) << 6) + d) * Lc + l] = v;
        }
      }
    }
  }
}

// f32 -> bf16 elementwise (n multiple of 1024; grid = n/1024)
__global__ __launch_bounds__(256) void conv_bf16(const float* __restrict__ in,
                                                 ushort_t* __restrict__ out) {
  int i = blockIdx.x * 256 + threadIdx.x;
  float4 v = *reinterpret_cast<const float4*>(&in[(size_t)i * 4]);
  ushort4 o;
  o.x = f2bf(v.x); o.y = f2bf(v.y); o.z = f2bf(v.z); o.w = f2bf(v.w);
  *reinterpret_cast<ushort4*>(&out[(size_t)i * 4]) = o;
}

// transpose-convert: in f32 [R][C] -> out bf16 rows [rowOff + c][r], row stride R
__global__ __launch_bounds__(256) void tconv(const float* __restrict__ in,
                                             ushort_t* __restrict__ out,
                                             int R, int C, int rowOff) {
  __shared__ float t[32][33];
  const int r0 = blockIdx.y << 5, c0 = blockIdx.x << 5;
  const int tr = threadIdx.x >> 5, tc = threadIdx.x & 31;
#pragma unroll
  for (int p = 0; p < 4; ++p)
    t[tr + p * 8][tc] = in[(size_t)(r0 + tr + p * 8) * C + c0 + tc];
  __syncthreads();
#pragma unroll
  for (int p = 0; p < 4; ++p)
    out[(size_t)(rowOff + c0 + tr + p * 8) * R + r0 + tc] = f2bf(t[tc][tr + p * 8]);
}

__global__ __launch_bounds__(256) void concat_bias(const float* __restrict__ bq,
                                                   const float* __restrict__ bk,
                                                   const float* __restrict__ bv,
                                                   float* __restrict__ o) {
  int i = blockIdx.x * 256 + threadIdx.x;
  o[i] = i < 512 ? bq[i] : (i < 1024 ? bk[i - 512] : bv[i - 1024]);
}

// M[b,h,l] = max_u(q.k_su) - mean_u(q.k_su); 16-lane group per (b,h,l).
__global__ __launch_bounds__(256) void compute_M_kernel(
    const float* __restrict__ Q, const float* __restrict__ K,
    const int* __restrict__ sidx, float* __restrict__ Mout) {
  const int tid = threadIdx.x;
  const int wave = tid >> 6, lane = tid & 63;
  const int g = lane >> 4, lg = lane & 15;
  const int gw = blockIdx.x * 16 + wave * 4 + g;  // (b*H+h)*L + l
  const int bh = gw >> 11, l = gw & (Lc - 1);
  const float4 q4 = *reinterpret_cast<const float4*>(&Q[((size_t)gw << 6) + (lg << 2)]);
  const float* Kbase = K + ((size_t)bh << 17);  // bh * L * D
  const int* sp = sidx + l * Uc;
  float mx = -1e30f, sm = 0.f;
#pragma unroll 4
  for (int u = 0; u < Uc; ++u) {
    const int idx = sp[u];
    const float4 k4 = *reinterpret_cast<const float4*>(&Kbase[((size_t)idx << 6) + (lg << 2)]);
    float d = q4.x * k4.x + q4.y * k4.y + q4.z * k4.z + q4.w * k4.w;
#pragma unroll
    for (int off = 8; off > 0; off >>= 1) d += __shfl_xor(d, off);
    mx = fmaxf(mx, d);
    sm += d;
  }
  if (lg == 0) Mout[gw] = mx - sm * (1.f / Uc);
}

// Exact stable top-k via rank counting; grid = 32 bh * 8 chunks, 1 cand/thread.
__global__ __launch_bounds__(256) void topk_kernel(const float* __restrict__ Min,
                                                   int* __restrict__ Mtop) {
  __shared__ float sm[Lc];
  const int bh = blockIdx.x >> 3, chunk = blockIdx.x & 7;
  const int tid = threadIdx.x;
  for (int i = tid; i < Lc; i += 256) sm[i] = Min[bh * Lc + i];
  __syncthreads();
  const int cand = (chunk << 8) + tid;
  const float mv = sm[cand];
  int rank = 0;
  for (int j = 0; j < Lc; j += 4) {
    float4 w4 = *reinterpret_cast<const float4*>(&sm[j]);
    rank += (w4.x > mv || (w4.x == mv && (j + 0) < cand));
    rank += (w4.y > mv || (w4.y == mv && (j + 1) < cand));
    rank += (w4.z > mv || (w4.z == mv && (j + 2) < cand));
    rank += (w4.w > mv || (w4.w == mv && (j + 3) < cand));
  }
  if (rank < Uc) Mtop[bh * Uc + rank] = cand;
}

// ---------------------------------------------------------------------------
// Flash-chunk attention: block = (bh, chunk of 128 keys). K/V read ONCE.
// Writes per-chunk softmax partials (m, l, o); attn_combine merges them.
// ---------------------------------------------------------------------------
__global__ __launch_bounds__(256, 2) void attn_flash(
    const float* __restrict__ Q, const float* __restrict__ K,
    const float* __restrict__ V, const int* __restrict__ Mtop,
    float* __restrict__ m_p, float* __restrict__ l_p, float* __restrict__ o_p) {
  __shared__ float qs[Uc][Dc];      // 10240 B
  __shared__ float p[Uc][132];      // 21120 B (pad 4 -> 16B-aligned rows)
  __shared__ float kv[128 * 68];    // 34816 B: K as [128][68], then Vt as [64][132]
  const int tid = threadIdx.x;
  const int bh = blockIdx.x >> 4, chunk = blockIdx.x & 15;
  const int kk0 = chunk << 7;
  const float* Kb = K + ((size_t)bh << 17);
  const float* Vb = V + ((size_t)bh << 17);
  // stage 40 selected Q rows (640 float4)
  for (int i = tid; i < Uc * 16; i += 256) {
    int u = i >> 4, c = (i & 15) << 2;
    int lsel = Mtop[bh * Uc + u];
    *reinterpret_cast<float4*>(&qs[u][c]) =
        *reinterpret_cast<const float4*>(&Q[((size_t)(bh * Lc + lsel) << 6) + c]);
  }
  // stage K chunk [128][68]
  for (int i = tid; i < 128 * 16; i += 256) {
    int r = i >> 4, c = (i & 15) << 2;
    *reinterpret_cast<float4*>(&kv[r * 68 + c]) =
        *reinterpret_cast<const float4*>(&Kb[((size_t)(kk0 + r) << 6) + c]);
  }
  __syncthreads();
  // scores: thread (sgrp, kk); K row in regs, broadcast q reads
  {
    const int sgrp = tid >> 7, kk = tid & 127;
    float4 krow[16];
#pragma unroll
    for (int c = 0; c < 16; ++c)
      krow[c] = *reinterpret_cast<const float4*>(&kv[kk * 68 + (c << 2)]);
    for (int u = sgrp * 20; u < sgrp * 20 + 20; ++u) {
      float acc = 0.f;
#pragma unroll
      for (int c = 0; c < 16; ++c) {
        float4 q4 = *reinterpret_cast<const float4*>(&qs[u][c << 2]);
        acc += q4.x * krow[c].x + q4.y * krow[c].y + q4.z * krow[c].z + q4.w * krow[c].w;
      }
      p[u][kk] = acc * 0.125f;  // 1/sqrt(64)
    }
  }
  __syncthreads();
  // per-u chunk softmax partials
  if (tid < Uc) {
    float mx = -1e30f;
    for (int k2 = 0; k2 < 128; ++k2) mx = fmaxf(mx, p[tid][k2]);
    float ls = 0.f;
    for (int k2 = 0; k2 < 128; ++k2) {
      float e = __expf(p[tid][k2] - mx);
      p[tid][k2] = e;
      ls += e;
    }
    m_p[(bh * Uc + tid) * 16 + chunk] = mx;
    l_p[(bh * Uc + tid) * 16 + chunk] = ls;
  }
  __syncthreads();
  // stage V transposed: Vt[d][kk] (reuses kv)
  for (int i = tid; i < 128 * 64; i += 256) {
    int r = i >> 6, d = i & 63;
    kv[d * 132 + r] = Vb[((size_t)(kk0 + r) << 6) + d];
  }
  __syncthreads();
  // ctx partial: thread (cgrp, d); Vt row in regs, broadcast p reads
  {
    const int cgrp = tid >> 6, d = tid & 63;
    float4 vrow[32];
#pragma unroll
    for (int c = 0; c < 32; ++c)
      vrow[c] = *reinterpret_cast<const float4*>(&kv[d * 132 + (c << 2)]);
    for (int u = cgrp * 10; u < cgrp * 10 + 10; ++u) {
      float acc = 0.f;
#pragma unroll
      for (int c = 0; c < 32; ++c) {
        float4 pv = *reinterpret_cast<const float4*>(&p[u][c << 2]);
        acc += pv.x * vrow[c].x + pv.y * vrow[c].y + pv.z * vrow[c].z + pv.w * vrow[c].w;
      }
      o_p[((size_t)(bh * Uc + u) * 16 + chunk) * 64 + d] = acc;
    }
  }
}

// merge 16 chunk partials; write bf16 ctx into CTXb at selected rows
__global__ __launch_bounds__(256) void attn_combine(
    const float* __restrict__ m_p, const float* __restrict__ l_p,
    const float* __restrict__ o_p, const int* __restrict__ Mtop,
    ushort_t* __restrict__ ctxb) {
  const int w = (blockIdx.x * 256 + threadIdx.x) >> 6;  // bh*40+u
  const int lane = threadIdx.x & 63;
  const float* mp = m_p + w * 16;
  const float* lp = l_p + w * 16;
  float M = -1e30f;
#pragma unroll
  for (int c = 0; c < 16; ++c) M = fmaxf(M, mp[c]);
  float denom = 0.f;
  float wgt[16];
#pragma unroll
  for (int c = 0; c < 16; ++c) {
    wgt[c] = __expf(mp[c] - M);
    denom += lp[c] * wgt[c];
  }
  float acc = 0.f;
#pragma unroll
  for (int c = 0; c < 16; ++c)
    acc += o_p[((size_t)w * 16 + c) * 64 + lane] * wgt[c];
  const int bh = w / Uc;
  const int b = bh >> 3, h = bh & 7;
  const int lsel = Mtop[w];
  ctxb[(size_t)(b * Lc + lsel) * DMc + (h << 6) + lane] = f2bf(acc / denom);
}

__global__ __launch_bounds__(64) void vmean_kernel(const float* __restrict__ V,
                                                   float* __restrict__ vmean) {
  int blk = blockIdx.x;  // B*H*8
  int bh = blk >> 3, c = blk & 7;
  int lane = threadIdx.x;
  float sm = 0.f;
  int lbase = c << 8;
  for (int l = lbase; l < lbase + 256; ++l)
    sm += V[((size_t)(bh * Lc + l) << 6) + lane];
  atomicAdd(&vmean[(bh << 6) + lane], sm * (1.f / Lc));
}

// ctxb[b,l,h*64+d] = bf16(vmean[b*512 + (h*64+d)])
__global__ __launch_bounds__(256) void build_ctx_kernel(const float* __restrict__ vmean,
                                                        ushort_t* __restrict__ ctxb) {
  int idx = blockIdx.x * 256 + threadIdx.x;
  ctxb[idx] = f2bf(vmean[((idx >> 20) << 9) + (idx & 511)]);
}

// out = LayerNorm(resid + yin) * g + b ; optional bf16 copy. In-place safe.
__global__ __launch_bounds__(256) void add_ln_kernel(
    const float* __restrict__ resid, const float* __restrict__ yin,
    const float* __restrict__ g, const float* __restrict__ bbias,
    float* __restrict__ out, ushort_t* __restrict__ outb) {
  __shared__ float vals[DMc];
  __shared__ float red[4];
  int row = blockIdx.x, tid = threadIdx.x;
  size_t base = (size_t)row * DMc;
  float lsum = 0.f;
  for (int c = tid; c < DMc; c += 256) {
    float t = resid[base + c] + yin[base + c];
    vals[c] = t;
    lsum += t;
  }
  lsum = wave_sum(lsum);
  if ((tid & 63) == 0) red[tid >> 6] = lsum;
  __syncthreads();
  float mean = (red[0] + red[1] + red[2] + red[3]) * (1.f / DMc);
  __syncthreads();
  float lv = 0.f;
  for (int c = tid; c < DMc; c += 256) {
    float dv = vals[c] - mean;
    lv += dv * dv;
  }
  lv = wave_sum(lv);
  if ((tid & 63) == 0) red[tid >> 6] = lv;
  __syncthreads();
  float inv = rsqrtf((red[0] + red[1] + red[2] + red[3]) * (1.f / DMc) + 1e-5f);
  for (int c = tid; c < DMc; c += 256) {
    float o = (vals[c] - mean) * inv * g[c] + bbias[c];
    out[base + c] = o;
    if (outb) outb[base + c] = f2bf(o);
  }
}

extern "C" void kernel_launch(void* const* d_in, const int* in_sizes, int n_in,
                              void* d_out, int out_size, void* d_ws, size_t ws_size,
                              hipStream_t stream) {
  (void)in_sizes; (void)n_in; (void)out_size; (void)ws_size;
  const float* x   = (const float*)d_in[0];
  const float* Wq  = (const float*)d_in[1];
  const float* bq  = (const float*)d_in[2];
  const float* Wk  = (const float*)d_in[3];
  const float* bk  = (const float*)d_in[4];
  const float* Wv  = (const float*)d_in[5];
  const float* bv  = (const float*)d_in[6];
  const float* Wo  = (const float*)d_in[7];
  const float* bo  = (const float*)d_in[8];
  const float* Wc1 = (const float*)d_in[9];
  const float* bc1 = (const float*)d_in[10];
  const float* Wc2 = (const float*)d_in[11];
  const float* bc2 = (const float*)d_in[12];
  const float* g1  = (const float*)d_in[13];
  const float* b1  = (const float*)d_in[14];
  const float* g2  = (const float*)d_in[15];
  const float* b2  = (const float*)d_in[16];
  const int* sidx  = (const int*)d_in[17];
  float* out = (float*)d_out;

  float* ws = (float*)d_ws;
  // f32-word offsets
  float* Qb     = ws;                       // (B,H,L,D) 4M
  float* Kb     = ws + 4194304;             // 4M
  float* Vb     = ws + 8388608;             // 4M
  // ws+12582912 .. +16777216: attn partials (early) / X1b bf16 (late) — time-disjoint
  float* m_p    = ws + 12582912;            // 20480
  float* l_p    = ws + 12603392;            // 20480
  float* o_p    = ws + 12623872;            // 1,310,720
  float* X1     = ws + 16777216;            // 4M
  ushort_t* xb   = (ushort_t*)(ws + 20971520);  // [8192][512] bf16 (2M words)
  ushort_t* Wqkvt= (ushort_t*)(ws + 23068672);  // [1536][512] bf16
  ushort_t* Wot  = (ushort_t*)(ws + 23461888);  // [512][512] bf16
  ushort_t* Wc1b = (ushort_t*)(ws + 23592960);  // [2048][512] bf16
  ushort_t* Wc2b = (ushort_t*)(ws + 24117248);  // [512][2048] bf16
  float* bqkv   = ws + 24641536;            // 1536
  float* Mb     = ws + 24643072;            // 65536
  float* vmean  = ws + 24708608;            // 2048
  int* Mtop     = (int*)(ws + 24710656);    // 1280
  // aliases (producer runs strictly after last consumer of the dead buffer)
  ushort_t* CTXb = (ushort_t*)Vb;               // bf16 [8192][512], after vmean
  ushort_t* X1b  = (ushort_t*)(ws + 12582912);  // bf16 [8192][512], after combine
  ushort_t* Yb   = (ushort_t*)Qb;               // bf16 [8192][2048], after attn

  dim3 blk(256);
  conv_bf16<<<4096, blk, 0, stream>>>(x, xb);
  tconv<<<dim3(16, 16), blk, 0, stream>>>(Wq, Wqkvt, 512, 512, 0);
  tconv<<<dim3(16, 16), blk, 0, stream>>>(Wk, Wqkvt, 512, 512, 512);
  tconv<<<dim3(16, 16), blk, 0, stream>>>(Wv, Wqkvt, 512, 512, 1024);
  tconv<<<dim3(16, 16), blk, 0, stream>>>(Wo, Wot, 512, 512, 0);
  conv_bf16<<<1024, blk, 0, stream>>>(Wc1, Wc1b);
  conv_bf16<<<1024, blk, 0, stream>>>(Wc2, Wc2b);
  concat_bias<<<6, blk, 0, stream>>>(bq, bk, bv, bqkv);

  gemm_mfma<2><<<dim3(12, 64), blk, 0, stream>>>(xb, Wqkvt, bqkv, nullptr, nullptr,
                                                 Qb, Kb, Vb, nullptr, NT, 1536, DMc);
  compute_M_kernel<<<4096, blk, 0, stream>>>(Qb, Kb, sidx, Mb);
  topk_kernel<<<256, blk, 0, stream>>>(Mb, Mtop);
  attn_flash<<<512, blk, 0, stream>>>(Qb, Kb, Vb, Mtop, m_p, l_p, o_p);
  hipMemsetAsync(vmean, 0, Bc * Hc * Dc * sizeof(float), stream);
  vmean_kernel<<<Bc * Hc * 8, dim3(64), 0, stream>>>(Vb, vmean);
  build_ctx_kernel<<<16384, blk, 0, stream>>>(vmean, CTXb);
  attn_combine<<<320, blk, 0, stream>>>(m_p, l_p, o_p, Mtop, CTXb);

  gemm_mfma<0><<<dim3(4, 64), blk, 0, stream>>>(CTXb, Wot, bo, out, nullptr,
                                                nullptr, nullptr, nullptr, nullptr,
                                                NT, DMc, DMc);
  add_ln_kernel<<<NT, blk, 0, stream>>>(x, out, g1, b1, X1, X1b);
  gemm_mfma<1><<<dim3(16, 64), blk, 0, stream>>>(X1b, Wc1b, bc1, nullptr, Yb,
                                                 nullptr, nullptr, nullptr, nullptr,
                                                 NT, DFFc, DMc);
  gemm_mfma<0><<<dim3(4, 64), blk, 0, stream>>>(Yb, Wc2b, bc2, out, nullptr,
                                                nullptr, nullptr, nullptr, nullptr,
                                                NT, DMc, DFFc);
  add_ln_kernel<<<NT, blk, 0, stream>>>(X1, out, g2, b2, out, nullptr);
}

// Round 7
// 408.909 us; speedup vs baseline: 4.4576x; 1.0892x over previous
//
#include <hip/hip_runtime.h>
#include <math.h>

static constexpr int Bc = 4, Lc = 2048, DMc = 512, Hc = 8, Dc = 64, DFFc = 2048, Uc = 40;
static constexpr int NT = Bc * Lc; // 8192 tokens

typedef __attribute__((ext_vector_type(4))) float f32x4;
typedef __attribute__((ext_vector_type(8))) short bf16x8;
typedef unsigned short ushort_t;

__device__ __forceinline__ float wave_sum(float v) {
#pragma unroll
  for (int off = 32; off > 0; off >>= 1) v += __shfl_xor(v, off);
  return v;
}

__device__ __forceinline__ ushort_t f2bf(float f) {
  union { float f; unsigned int u; } c{f};
  unsigned int u = c.u + 0x7fff + ((c.u >> 16) & 1);
  return (ushort_t)(u >> 16);
}

__device__ __forceinline__ unsigned pk2bf(float a, float b) {
  return (unsigned)f2bf(a) | ((unsigned)f2bf(b) << 16);
}

__device__ __forceinline__ void gload16(const ushort_t* g, ushort_t* l) {
  __builtin_amdgcn_global_load_lds(
      (const __attribute__((address_space(1))) unsigned int*)g,
      (__attribute__((address_space(3))) unsigned int*)l, 16, 0, 0);
}

// ---------------------------------------------------------------------------
// bf16 MFMA GEMM, 128x128 tile, BK=32, 4 waves, m97 2-barrier structure.
// ---------------------------------------------------------------------------
template <int MODE>
__global__ __launch_bounds__(256) void gemm_mfma(
    const ushort_t* __restrict__ A, const ushort_t* __restrict__ Bt,
    const float* __restrict__ bias, float* __restrict__ Cf,
    ushort_t* __restrict__ Cb, float* __restrict__ Qo, float* __restrict__ Ko,
    float* __restrict__ Vo, float* __restrict__ Kt, int M, int N, int K) {
  __shared__ __align__(16) ushort_t As[128 * 32];
  __shared__ __align__(16) ushort_t Bs[128 * 32];
  const int tid = threadIdx.x;
  const int lane = tid & 63, wave = tid >> 6;
  const int m0 = blockIdx.y << 7, n0 = blockIdx.x << 7;
  const int wm = ((wave >> 1) << 6), wn = ((wave & 1) << 6);
  f32x4 acc[4][4] = {};
  const ushort_t* aSrc = A + (size_t)(m0 + (tid >> 2)) * K + ((tid & 3) << 3);
  const ushort_t* bSrc = Bt + (size_t)(n0 + (tid >> 2)) * K + ((tid & 3) << 3);
  ushort_t* aDst = As + wave * 512;  // wave-uniform LDS base; HW adds lane*16B
  ushort_t* bDst = Bs + wave * 512;
  const size_t aHalf = (size_t)64 * K, bHalf = (size_t)64 * K;
  for (int k0 = 0; k0 < K; k0 += 32) {
    gload16(aSrc + k0, aDst);
    gload16(aSrc + aHalf + k0, aDst + 2048);
    gload16(bSrc + k0, bDst);
    gload16(bSrc + bHalf + k0, bDst + 2048);
    __syncthreads();  // compiler drains vmcnt before s_barrier -> data ready
    bf16x8 af[4], bfr[4];
    const int fr = lane & 15, ko = (lane >> 4) << 3;
#pragma unroll
    for (int i = 0; i < 4; ++i) {
      af[i] = *reinterpret_cast<const bf16x8*>(&As[(wm + i * 16 + fr) * 32 + ko]);
      bfr[i] = *reinterpret_cast<const bf16x8*>(&Bs[(wn + i * 16 + fr) * 32 + ko]);
    }
#pragma unroll
    for (int i = 0; i < 4; ++i)
#pragma unroll
      for (int j = 0; j < 4; ++j)
        acc[i][j] = __builtin_amdgcn_mfma_f32_16x16x32_bf16(af[i], bfr[j], acc[i][j], 0, 0, 0);
    __syncthreads();
  }
  const int cr = (lane >> 4) << 2, cc = lane & 15;
#pragma unroll
  for (int j = 0; j < 4; ++j) {
    const int col = n0 + wn + j * 16 + cc;
    const float bsv = bias[col];
#pragma unroll
    for (int i = 0; i < 4; ++i) {
#pragma unroll
      for (int r = 0; r < 4; ++r) {
        const int row = m0 + wm + i * 16 + cr + r;
        float v = acc[i][j][r] + bsv;
        if (MODE == 0) {
          Cf[(size_t)row * N + col] = v;
        } else if (MODE == 1) {
          Cb[(size_t)row * N + col] = f2bf(fmaxf(v, 0.f));
        } else {
          const int which = col >> 9, h = (col >> 6) & 7, d = col & 63;
          const int b = row >> 11, l = row & (Lc - 1);
          const size_t o = ((size_t)(((b << 3) + h) << 11) + l) * 64 + d;
          float* dst = which == 0 ? Qo : (which == 1 ? Ko : Vo);
          dst[o] = v;
          if (which == 1 && Kt)
            Kt[((size_t)(((b << 3) + h) << 6) + d) * Lc + l] = v;
        }
      }
    }
  }
}

// f32 -> bf16 elementwise (n multiple of 1024; grid = n/1024)
__global__ __launch_bounds__(256) void conv_bf16(const float* __restrict__ in,
                                                 ushort_t* __restrict__ out) {
  int i = blockIdx.x * 256 + threadIdx.x;
  float4 v = *reinterpret_cast<const float4*>(&in[(size_t)i * 4]);
  ushort4 o;
  o.x = f2bf(v.x); o.y = f2bf(v.y); o.z = f2bf(v.z); o.w = f2bf(v.w);
  *reinterpret_cast<ushort4*>(&out[(size_t)i * 4]) = o;
}

// transpose-convert: in f32 [R][C] -> out bf16 rows [rowOff + c][r], row stride R
__global__ __launch_bounds__(256) void tconv(const float* __restrict__ in,
                                             ushort_t* __restrict__ out,
                                             int R, int C, int rowOff) {
  __shared__ float t[32][33];
  const int r0 = blockIdx.y << 5, c0 = blockIdx.x << 5;
  const int tr = threadIdx.x >> 5, tc = threadIdx.x & 31;
#pragma unroll
  for (int p = 0; p < 4; ++p)
    t[tr + p * 8][tc] = in[(size_t)(r0 + tr + p * 8) * C + c0 + tc];
  __syncthreads();
#pragma unroll
  for (int p = 0; p < 4; ++p)
    out[(size_t)(rowOff + c0 + tr + p * 8) * R + r0 + tc] = f2bf(t[tc][tr + p * 8]);
}

__global__ __launch_bounds__(256) void concat_bias(const float* __restrict__ bq,
                                                   const float* __restrict__ bk,
                                                   const float* __restrict__ bv,
                                                   float* __restrict__ o) {
  int i = blockIdx.x * 256 + threadIdx.x;
  o[i] = i < 512 ? bq[i] : (i < 1024 ? bk[i - 512] : bv[i - 1024]);
}

// M[b,h,l] = max_u(q.k_su) - mean_u(q.k_su); 16-lane group per (b,h,l).
__global__ __launch_bounds__(256) void compute_M_kernel(
    const float* __restrict__ Q, const float* __restrict__ K,
    const int* __restrict__ sidx, float* __restrict__ Mout) {
  const int tid = threadIdx.x;
  const int wave = tid >> 6, lane = tid & 63;
  const int g = lane >> 4, lg = lane & 15;
  const int gw = blockIdx.x * 16 + wave * 4 + g;  // (b*H+h)*L + l
  const int bh = gw >> 11, l = gw & (Lc - 1);
  const float4 q4 = *reinterpret_cast<const float4*>(&Q[((size_t)gw << 6) + (lg << 2)]);
  const float* Kbase = K + ((size_t)bh << 17);  // bh * L * D
  const int* sp = sidx + l * Uc;
  float mx = -1e30f, sm = 0.f;
#pragma unroll 4
  for (int u = 0; u < Uc; ++u) {
    const int idx = sp[u];
    const float4 k4 = *reinterpret_cast<const float4*>(&Kbase[((size_t)idx << 6) + (lg << 2)]);
    float d = q4.x * k4.x + q4.y * k4.y + q4.z * k4.z + q4.w * k4.w;
#pragma unroll
    for (int off = 8; off > 0; off >>= 1) d += __shfl_xor(d, off);
    mx = fmaxf(mx, d);
    sm += d;
  }
  if (lg == 0) Mout[gw] = mx - sm * (1.f / Uc);
}

// Exact stable top-k via rank counting; grid = 32 bh * 8 chunks, 1 cand/thread.
__global__ __launch_bounds__(256) void topk_kernel(const float* __restrict__ Min,
                                                   int* __restrict__ Mtop) {
  __shared__ float sm[Lc];
  const int bh = blockIdx.x >> 3, chunk = blockIdx.x & 7;
  const int tid = threadIdx.x;
  for (int i = tid; i < Lc; i += 256) sm[i] = Min[bh * Lc + i];
  __syncthreads();
  const int cand = (chunk << 8) + tid;
  const float mv = sm[cand];
  int rank = 0;
  for (int j = 0; j < Lc; j += 4) {
    float4 w4 = *reinterpret_cast<const float4*>(&sm[j]);
    rank += (w4.x > mv || (w4.x == mv && (j + 0) < cand));
    rank += (w4.y > mv || (w4.y == mv && (j + 1) < cand));
    rank += (w4.z > mv || (w4.z == mv && (j + 2) < cand));
    rank += (w4.w > mv || (w4.w == mv && (j + 3) < cand));
  }
  if (rank < Uc) Mtop[bh * Uc + rank] = cand;
}

// ---------------------------------------------------------------------------
// MFMA flash attention: block = (bh, chunk of 128 keys). K/V read ONCE.
// S = Qred(48pad)@K^T via 16x16x32 bf16 MFMA (12/wave), chunk softmax with
// cross-wave max, PV via MFMA (12/wave). Partials -> attn_combine.
// Fragment layouts identical to gemm_mfma (verified).
// ---------------------------------------------------------------------------
__global__ __launch_bounds__(256, 3) void attn_flash(
    const float* __restrict__ Q, const float* __restrict__ K,
    const float* __restrict__ V, const int* __restrict__ Mtop,
    float* __restrict__ m_p, float* __restrict__ l_p, float* __restrict__ o_p) {
  __shared__ __align__(16) ushort_t Qs[48 * 80];    // 7680 B, row stride 80
  __shared__ __align__(16) ushort_t KVs[128 * 80];  // 20480 B; Vt[64][144] overlays
  __shared__ __align__(16) ushort_t Ps[48 * 144];   // 13824 B, row stride 144
  __shared__ float mw[4][48];
  __shared__ float lw[4][48];
  const int tid = threadIdx.x;
  const int lane = tid & 63, w = tid >> 6;
  const int cc = lane & 15, hi = lane >> 4;
  const int bh = blockIdx.x >> 4, chunk = blockIdx.x & 15;
  const int kk0 = chunk << 7;
  const float* Qb = Q + ((size_t)bh << 17);
  const float* Kb = K + ((size_t)bh << 17);
  const float* Vb = V + ((size_t)bh << 17);

  // stage Qs (gathered selected rows; rows >= Uc zeroed) and Ks, bf16
  for (int i = tid; i < 48 * 16; i += 256) {
    const int r = i >> 4, c4 = (i & 15) << 2;
    uint2 pk{0u, 0u};
    if (r < Uc) {
      const int lsel = Mtop[bh * Uc + r];
      float4 v = *reinterpret_cast<const float4*>(&Qb[((size_t)lsel << 6) + c4]);
      pk.x = pk2bf(v.x, v.y); pk.y = pk2bf(v.z, v.w);
    }
    *reinterpret_cast<uint2*>(&Qs[r * 80 + c4]) = pk;
  }
  for (int i = tid; i < 128 * 16; i += 256) {
    const int r = i >> 4, c4 = (i & 15) << 2;
    float4 v = *reinterpret_cast<const float4*>(&Kb[((size_t)(kk0 + r) << 6) + c4]);
    uint2 pk{pk2bf(v.x, v.y), pk2bf(v.z, v.w)};
    *reinterpret_cast<uint2*>(&KVs[r * 80 + c4]) = pk;
  }
  __syncthreads();

  // S slice: wave w covers cols [w*32, w*32+32), K-dim 64 = 2 ksteps
  f32x4 sacc[3][2] = {};
#pragma unroll
  for (int s = 0; s < 2; ++s) {
    bf16x8 af[3], bk[2];
#pragma unroll
    for (int i = 0; i < 3; ++i)
      af[i] = *reinterpret_cast<const bf16x8*>(&Qs[(i * 16 + cc) * 80 + s * 32 + hi * 8]);
#pragma unroll
    for (int jj = 0; jj < 2; ++jj)
      bk[jj] = *reinterpret_cast<const bf16x8*>(&KVs[(w * 32 + jj * 16 + cc) * 80 + s * 32 + hi * 8]);
#pragma unroll
    for (int i = 0; i < 3; ++i)
#pragma unroll
      for (int jj = 0; jj < 2; ++jj)
        sacc[i][jj] = __builtin_amdgcn_mfma_f32_16x16x32_bf16(af[i], bk[jj], sacc[i][jj], 0, 0, 0);
  }

  // per-wave row max (scaled)
  float mx[3][4];
#pragma unroll
  for (int i = 0; i < 3; ++i)
#pragma unroll
    for (int r = 0; r < 4; ++r)
      mx[i][r] = fmaxf(sacc[i][0][r], sacc[i][1][r]) * 0.125f;
#pragma unroll
  for (int off = 1; off < 16; off <<= 1)
#pragma unroll
    for (int i = 0; i < 3; ++i)
#pragma unroll
      for (int r = 0; r < 4; ++r)
        mx[i][r] = fmaxf(mx[i][r], __shfl_xor(mx[i][r], off));
  if (cc == 0)
#pragma unroll
    for (int i = 0; i < 3; ++i)
#pragma unroll
      for (int r = 0; r < 4; ++r) mw[w][i * 16 + (hi << 2) + r] = mx[i][r];
  __syncthreads();  // also: all MFMA reads of KVs done -> Vt overlay safe

  // final chunk max; p = exp(s*scale - m); Ps bf16; l partials
  float fm[3][4], ls[3][4];
#pragma unroll
  for (int i = 0; i < 3; ++i)
#pragma unroll
    for (int r = 0; r < 4; ++r) {
      const int row = i * 16 + (hi << 2) + r;
      fm[i][r] = fmaxf(fmaxf(mw[0][row], mw[1][row]), fmaxf(mw[2][row], mw[3][row]));
      ls[i][r] = 0.f;
    }
#pragma unroll
  for (int i = 0; i < 3; ++i)
#pragma unroll
    for (int jj = 0; jj < 2; ++jj)
#pragma unroll
      for (int r = 0; r < 4; ++r) {
        float p = __expf(sacc[i][jj][r] * 0.125f - fm[i][r]);
        ls[i][r] += p;
        Ps[(i * 16 + (hi << 2) + r) * 144 + w * 32 + jj * 16 + cc] = f2bf(p);
      }
#pragma unroll
  for (int off = 1; off < 16; off <<= 1)
#pragma unroll
    for (int i = 0; i < 3; ++i)
#pragma unroll
      for (int r = 0; r < 4; ++r) ls[i][r] += __shfl_xor(ls[i][r], off);
  if (cc == 0)
#pragma unroll
    for (int i = 0; i < 3; ++i)
#pragma unroll
      for (int r = 0; r < 4; ++r) lw[w][i * 16 + (hi << 2) + r] = ls[i][r];

  // stage V transposed over dead K: Vt[d][k], row stride 144 bf16
  {
    ushort_t* Vt = KVs;
    for (int i = tid; i < 128 * 16; i += 256) {
      const int k = i >> 4, c4 = (i & 15) << 2;
      float4 v = *reinterpret_cast<const float4*>(&Vb[((size_t)(kk0 + k) << 6) + c4]);
      Vt[(c4 + 0) * 144 + k] = f2bf(v.x);
      Vt[(c4 + 1) * 144 + k] = f2bf(v.y);
      Vt[(c4 + 2) * 144 + k] = f2bf(v.z);
      Vt[(c4 + 3) * 144 + k] = f2bf(v.w);
    }
  }
  __syncthreads();

  // PV: wave w covers out cols [w*16, w*16+16); K-dim 128 = 4 ksteps
  f32x4 oacc[3] = {};
#pragma unroll
  for (int s = 0; s < 4; ++s) {
    bf16x8 ap[3], bv;
#pragma unroll
    for (int i = 0; i < 3; ++i)
      ap[i] = *reinterpret_cast<const bf16x8*>(&Ps[(i * 16 + cc) * 144 + s * 32 + hi * 8]);
    bv = *reinterpret_cast<const bf16x8*>(&KVs[(w * 16 + cc) * 144 + s * 32 + hi * 8]);
#pragma unroll
    for (int i = 0; i < 3; ++i)
      oacc[i] = __builtin_amdgcn_mfma_f32_16x16x32_bf16(ap[i], bv, oacc[i], 0, 0, 0);
  }
#pragma unroll
  for (int i = 0; i < 3; ++i)
#pragma unroll
    for (int r = 0; r < 4; ++r) {
      const int row = i * 16 + (hi << 2) + r;
      if (row < Uc)
        o_p[((size_t)((bh * Uc + row) * 16 + chunk) << 6) + w * 16 + cc] = oacc[i][r];
    }
  if (w == 0 && cc == 0)
#pragma unroll
    for (int i = 0; i < 3; ++i)
#pragma unroll
      for (int r = 0; r < 4; ++r) {
        const int row = i * 16 + (hi << 2) + r;
        if (row < Uc) {
          m_p[(bh * Uc + row) * 16 + chunk] = fm[i][r];
          l_p[(bh * Uc + row) * 16 + chunk] =
              lw[0][row] + lw[1][row] + lw[2][row] + lw[3][row];
        }
      }
}

// merge 16 chunk partials; write bf16 ctx into CTXb at selected rows
__global__ __launch_bounds__(256) void attn_combine(
    const float* __restrict__ m_p, const float* __restrict__ l_p,
    const float* __restrict__ o_p, const int* __restrict__ Mtop,
    ushort_t* __restrict__ ctxb) {
  const int w = (blockIdx.x * 256 + threadIdx.x) >> 6;  // bh*40+u
  const int lane = threadIdx.x & 63;
  const float* mp = m_p + w * 16;
  const float* lp = l_p + w * 16;
  float M = -1e30f;
#pragma unroll
  for (int c = 0; c < 16; ++c) M = fmaxf(M, mp[c]);
  float denom = 0.f;
  float wgt[16];
#pragma unroll
  for (int c = 0; c < 16; ++c) {
    wgt[c] = __expf(mp[c] - M);
    denom += lp[c] * wgt[c];
  }
  float acc = 0.f;
#pragma unroll
  for (int c = 0; c < 16; ++c)
    acc += o_p[((size_t)w * 16 + c) * 64 + lane] * wgt[c];
  const int bh = w / Uc;
  const int b = bh >> 3, h = bh & 7;
  const int lsel = Mtop[w];
  ctxb[(size_t)(b * Lc + lsel) * DMc + (h << 6) + lane] = f2bf(acc / denom);
}

__global__ __launch_bounds__(64) void vmean_kernel(const float* __restrict__ V,
                                                   float* __restrict__ vmean) {
  int blk = blockIdx.x;  // B*H*8
  int bh = blk >> 3, c = blk & 7;
  int lane = threadIdx.x;
  float sm = 0.f;
  int lbase = c << 8;
  for (int l = lbase; l < lbase + 256; ++l)
    sm += V[((size_t)(bh * Lc + l) << 6) + lane];
  atomicAdd(&vmean[(bh << 6) + lane], sm * (1.f / Lc));
}

// ctxb[b,l,h*64+d] = bf16(vmean[b*512 + (h*64+d)])
__global__ __launch_bounds__(256) void build_ctx_kernel(const float* __restrict__ vmean,
                                                        ushort_t* __restrict__ ctxb) {
  int idx = blockIdx.x * 256 + threadIdx.x;
  ctxb[idx] = f2bf(vmean[((idx >> 20) << 9) + (idx & 511)]);
}

// out = LayerNorm(resid + yin) * g + b ; optional bf16 copy. In-place safe.
__global__ __launch_bounds__(256) void add_ln_kernel(
    const float* __restrict__ resid, const float* __restrict__ yin,
    const float* __restrict__ g, const float* __restrict__ bbias,
    float* __restrict__ out, ushort_t* __restrict__ outb) {
  __shared__ float vals[DMc];
  __shared__ float red[4];
  int row = blockIdx.x, tid = threadIdx.x;
  size_t base = (size_t)row * DMc;
  float lsum = 0.f;
  for (int c = tid; c < DMc; c += 256) {
    float t = resid[base + c] + yin[base + c];
    vals[c] = t;
    lsum += t;
  }
  lsum = wave_sum(lsum);
  if ((tid & 63) == 0) red[tid >> 6] = lsum;
  __syncthreads();
  float mean = (red[0] + red[1] + red[2] + red[3]) * (1.f / DMc);
  __syncthreads();
  float lv = 0.f;
  for (int c = tid; c < DMc; c += 256) {
    float dv = vals[c] - mean;
    lv += dv * dv;
  }
  lv = wave_sum(lv);
  if ((tid & 63) == 0) red[tid >> 6] = lv;
  __syncthreads();
  float inv = rsqrtf((red[0] + red[1] + red[2] + red[3]) * (1.f / DMc) + 1e-5f);
  for (int c = tid; c < DMc; c += 256) {
    float o = (vals[c] - mean) * inv * g[c] + bbias[c];
    out[base + c] = o;
    if (outb) outb[base + c] = f2bf(o);
  }
}

extern "C" void kernel_launch(void* const* d_in, const int* in_sizes, int n_in,
                              void* d_out, int out_size, void* d_ws, size_t ws_size,
                              hipStream_t stream) {
  (void)in_sizes; (void)n_in; (void)out_size; (void)ws_size;
  const float* x   = (const float*)d_in[0];
  const float* Wq  = (const float*)d_in[1];
  const float* bq  = (const float*)d_in[2];
  const float* Wk  = (const float*)d_in[3];
  const float* bk  = (const float*)d_in[4];
  const float* Wv  = (const float*)d_in[5];
  const float* bv  = (const float*)d_in[6];
  const float* Wo  = (const float*)d_in[7];
  const float* bo  = (const float*)d_in[8];
  const float* Wc1 = (const float*)d_in[9];
  const float* bc1 = (const float*)d_in[10];
  const float* Wc2 = (const float*)d_in[11];
  const float* bc2 = (const float*)d_in[12];
  const float* g1  = (const float*)d_in[13];
  const float* b1  = (const float*)d_in[14];
  const float* g2  = (const float*)d_in[15];
  const float* b2  = (const float*)d_in[16];
  const int* sidx  = (const int*)d_in[17];
  float* out = (float*)d_out;

  float* ws = (float*)d_ws;
  // f32-word offsets
  float* Qb     = ws;                       // (B,H,L,D) 4M
  float* Kb     = ws + 4194304;             // 4M
  float* Vb     = ws + 8388608;             // 4M
  // ws+12582912 .. +16777216: attn partials (early) / X1b bf16 (late) — time-disjoint
  float* m_p    = ws + 12582912;            // 20480
  float* l_p    = ws + 12603392;            // 20480
  float* o_p    = ws + 12623872;            // 1,310,720
  float* X1     = ws + 16777216;            // 4M
  ushort_t* xb   = (ushort_t*)(ws + 20971520);  // [8192][512] bf16 (2M words)
  ushort_t* Wqkvt= (ushort_t*)(ws + 23068672);  // [1536][512] bf16
  ushort_t* Wot  = (ushort_t*)(ws + 23461888);  // [512][512] bf16
  ushort_t* Wc1b = (ushort_t*)(ws + 23592960);  // [2048][512] bf16
  ushort_t* Wc2b = (ushort_t*)(ws + 24117248);  // [512][2048] bf16
  float* bqkv   = ws + 24641536;            // 1536
  float* Mb     = ws + 24643072;            // 65536
  float* vmean  = ws + 24708608;            // 2048
  int* Mtop     = (int*)(ws + 24710656);    // 1280
  // aliases (producer runs strictly after last consumer of the dead buffer)
  ushort_t* CTXb = (ushort_t*)Vb;               // bf16 [8192][512], after vmean
  ushort_t* X1b  = (ushort_t*)(ws + 12582912);  // bf16 [8192][512], after combine
  ushort_t* Yb   = (ushort_t*)Qb;               // bf16 [8192][2048], after attn

  dim3 blk(256);
  conv_bf16<<<4096, blk, 0, stream>>>(x, xb);
  tconv<<<dim3(16, 16), blk, 0, stream>>>(Wq, Wqkvt, 512, 512, 0);
  tconv<<<dim3(16, 16), blk, 0, stream>>>(Wk, Wqkvt, 512, 512, 512);
  tconv<<<dim3(16, 16), blk, 0, stream>>>(Wv, Wqkvt, 512, 512, 1024);
  tconv<<<dim3(16, 16), blk, 0, stream>>>(Wo, Wot, 512, 512, 0);
  conv_bf16<<<1024, blk, 0, stream>>>(Wc1, Wc1b);
  conv_bf16<<<1024, blk, 0, stream>>>(Wc2, Wc2b);
  concat_bias<<<6, blk, 0, stream>>>(bq, bk, bv, bqkv);

  gemm_mfma<2><<<dim3(12, 64), blk, 0, stream>>>(xb, Wqkvt, bqkv, nullptr, nullptr,
                                                 Qb, Kb, Vb, nullptr, NT, 1536, DMc);
  compute_M_kernel<<<4096, blk, 0, stream>>>(Qb, Kb, sidx, Mb);
  topk_kernel<<<256, blk, 0, stream>>>(Mb, Mtop);
  attn_flash<<<512, blk, 0, stream>>>(Qb, Kb, Vb, Mtop, m_p, l_p, o_p);
  hipMemsetAsync(vmean, 0, Bc * Hc * Dc * sizeof(float), stream);
  vmean_kernel<<<Bc * Hc * 8, dim3(64), 0, stream>>>(Vb, vmean);
  build_ctx_kernel<<<16384, blk, 0, stream>>>(vmean, CTXb);
  attn_combine<<<320, blk, 0, stream>>>(m_p, l_p, o_p, Mtop, CTXb);

  gemm_mfma<0><<<dim3(4, 64), blk, 0, stream>>>(CTXb, Wot, bo, out, nullptr,
                                                nullptr, nullptr, nullptr, nullptr,
                                                NT, DMc, DMc);
  add_ln_kernel<<<NT, blk, 0, stream>>>(x, out, g1, b1, X1, X1b);
  gemm_mfma<1><<<dim3(16, 64), blk, 0, stream>>>(X1b, Wc1b, bc1, nullptr, Yb,
                                                 nullptr, nullptr, nullptr, nullptr,
                                                 NT, DFFc, DMc);
  gemm_mfma<0><<<dim3(4, 64), blk, 0, stream>>>(Yb, Wc2b, bc2, out, nullptr,
                                                nullptr, nullptr, nullptr, nullptr,
                                                NT, DMc, DFFc);
  add_ln_kernel<<<NT, blk, 0, stream>>>(X1, out, g2, b2, out, nullptr);
}

// Round 10
// 381.985 us; speedup vs baseline: 4.7718x; 1.0705x over previous
//
#include <hip/hip_runtime.h>
#include <math.h>

static constexpr int Bc = 4, Lc = 2048, DMc = 512, Hc = 8, Dc = 64, DFFc = 2048, Uc = 40;
static constexpr int NT = Bc * Lc; // 8192 tokens

typedef __attribute__((ext_vector_type(4))) float f32x4;
typedef __attribute__((ext_vector_type(8))) short bf16x8;
typedef unsigned short ushort_t;

__device__ __forceinline__ float wave_sum(float v) {
#pragma unroll
  for (int off = 32; off > 0; off >>= 1) v += __shfl_xor(v, off);
  return v;
}

__device__ __forceinline__ ushort_t f2bf(float f) {
  union { float f; unsigned int u; } c{f};
  unsigned int u = c.u + 0x7fff + ((c.u >> 16) & 1);
  return (ushort_t)(u >> 16);
}

__device__ __forceinline__ float bf2f(ushort_t b) {
  union { unsigned int u; float f; } c{(unsigned int)b << 16};
  return c.f;
}

__device__ __forceinline__ void gload16(const ushort_t* g, ushort_t* l) {
  __builtin_amdgcn_global_load_lds(
      (const __attribute__((address_space(1))) unsigned int*)g,
      (__attribute__((address_space(3))) unsigned int*)l, 16, 0, 0);
}

// ---------------------------------------------------------------------------
// bf16 MFMA GEMM, 128x128 tile, BK=32, 4 waves, m97 structure + XCD swizzle.
// MODE 0: Cf f32. MODE 1: Cb bf16 relu. MODE 2: QKV scatter -> bf16 (B,H,L,D).
// ---------------------------------------------------------------------------
template <int MODE>
__global__ __launch_bounds__(256) void gemm_mfma(
    const ushort_t* __restrict__ A, const ushort_t* __restrict__ Bt,
    const float* __restrict__ bias, float* __restrict__ Cf,
    ushort_t* __restrict__ Cb, ushort_t* __restrict__ Qo, ushort_t* __restrict__ Ko,
    ushort_t* __restrict__ Vo, int M, int N, int K) {
  __shared__ __align__(16) ushort_t As[128 * 32];
  __shared__ __align__(16) ushort_t Bs[128 * 32];
  const int tid = threadIdx.x;
  const int lane = tid & 63, wave = tid >> 6;
  // XCD-aware bijective swizzle (nwg % 8 == 0 for all our grids)
  const int nwg = gridDim.x * gridDim.y;
  const int lin = blockIdx.y * gridDim.x + blockIdx.x;
  const int swz = (lin & 7) * (nwg >> 3) + (lin >> 3);
  const int m0 = (swz / gridDim.x) << 7, n0 = (swz % gridDim.x) << 7;
  const int wm = ((wave >> 1) << 6), wn = ((wave & 1) << 6);
  f32x4 acc[4][4] = {};
  const ushort_t* aSrc = A + (size_t)(m0 + (tid >> 2)) * K + ((tid & 3) << 3);
  const ushort_t* bSrc = Bt + (size_t)(n0 + (tid >> 2)) * K + ((tid & 3) << 3);
  ushort_t* aDst = As + wave * 512;  // wave-uniform LDS base; HW adds lane*16B
  ushort_t* bDst = Bs + wave * 512;
  const size_t aHalf = (size_t)64 * K, bHalf = (size_t)64 * K;
  for (int k0 = 0; k0 < K; k0 += 32) {
    gload16(aSrc + k0, aDst);
    gload16(aSrc + aHalf + k0, aDst + 2048);
    gload16(bSrc + k0, bDst);
    gload16(bSrc + bHalf + k0, bDst + 2048);
    __syncthreads();  // compiler drains vmcnt before s_barrier -> data ready
    bf16x8 af[4], bfr[4];
    const int fr = lane & 15, ko = (lane >> 4) << 3;
#pragma unroll
    for (int i = 0; i < 4; ++i) {
      af[i] = *reinterpret_cast<const bf16x8*>(&As[(wm + i * 16 + fr) * 32 + ko]);
      bfr[i] = *reinterpret_cast<const bf16x8*>(&Bs[(wn + i * 16 + fr) * 32 + ko]);
    }
#pragma unroll
    for (int i = 0; i < 4; ++i)
#pragma unroll
      for (int j = 0; j < 4; ++j)
        acc[i][j] = __builtin_amdgcn_mfma_f32_16x16x32_bf16(af[i], bfr[j], acc[i][j], 0, 0, 0);
    __syncthreads();
  }
  const int cr = (lane >> 4) << 2, cc = lane & 15;
#pragma unroll
  for (int j = 0; j < 4; ++j) {
    const int col = n0 + wn + j * 16 + cc;
    const float bsv = bias[col];
#pragma unroll
    for (int i = 0; i < 4; ++i) {
#pragma unroll
      for (int r = 0; r < 4; ++r) {
        const int row = m0 + wm + i * 16 + cr + r;
        float v = acc[i][j][r] + bsv;
        if (MODE == 0) {
          Cf[(size_t)row * N + col] = v;
        } else if (MODE == 1) {
          Cb[(size_t)row * N + col] = f2bf(fmaxf(v, 0.f));
        } else {
          const int which = col >> 9, h = (col >> 6) & 7, d = col & 63;
          const int b = row >> 11, l = row & (Lc - 1);
          const size_t o = ((size_t)(((b << 3) + h) << 11) + l) * 64 + d;
          ushort_t* dst = which == 0 ? Qo : (which == 1 ? Ko : Vo);
          dst[o] = f2bf(v);
        }
      }
    }
  }
}

// f32 -> bf16 elementwise (n multiple of 1024; grid = n/1024)
__global__ __launch_bounds__(256) void conv_bf16(const float* __restrict__ in,
                                                 ushort_t* __restrict__ out) {
  int i = blockIdx.x * 256 + threadIdx.x;
  float4 v = *reinterpret_cast<const float4*>(&in[(size_t)i * 4]);
  ushort4 o;
  o.x = f2bf(v.x); o.y = f2bf(v.y); o.z = f2bf(v.z); o.w = f2bf(v.w);
  *reinterpret_cast<ushort4*>(&out[(size_t)i * 4]) = o;
}

// transpose-convert: in f32 [R][C] -> out bf16 rows [rowOff + c][r], row stride R
__global__ __launch_bounds__(256) void tconv(const float* __restrict__ in,
                                             ushort_t* __restrict__ out,
                                             int R, int C, int rowOff) {
  __shared__ float t[32][33];
  const int r0 = blockIdx.y << 5, c0 = blockIdx.x << 5;
  const int tr = threadIdx.x >> 5, tc = threadIdx.x & 31;
#pragma unroll
  for (int p = 0; p < 4; ++p)
    t[tr + p * 8][tc] = in[(size_t)(r0 + tr + p * 8) * C + c0 + tc];
  __syncthreads();
#pragma unroll
  for (int p = 0; p < 4; ++p)
    out[(size_t)(rowOff + c0 + tr + p * 8) * R + r0 + tc] = f2bf(t[tc][tr + p * 8]);
}

__global__ __launch_bounds__(256) void concat_bias(const float* __restrict__ bq,
                                                   const float* __restrict__ bk,
                                                   const float* __restrict__ bv,
                                                   float* __restrict__ o) {
  int i = blockIdx.x * 256 + threadIdx.x;
  o[i] = i < 512 ? bq[i] : (i < 1024 ? bk[i - 512] : bv[i - 1024]);
}

// M[b,h,l] = max_u(q.k_su) - mean_u(q.k_su); 16-lane group per (b,h,l).
// bf16 Q/K; XCD-grouped: all 128 blocks of one bh land on one XCD.
__global__ __launch_bounds__(256) void compute_M_kernel(
    const ushort_t* __restrict__ Q, const ushort_t* __restrict__ K,
    const int* __restrict__ sidx, float* __restrict__ Mout) {
  const int tid = threadIdx.x;
  const int wave = tid >> 6, lane = tid & 63;
  const int g = lane >> 4, lg = lane & 15;
  const int p = blockIdx.x;                 // 4096
  const int xcd = p & 7, j = p >> 3;        // j: 0..511
  const int bh = xcd + ((j >> 7) << 3);     // 4 bh per XCD
  const int inner = j & 127;
  const int gw = (bh << 11) + (inner << 4) + wave * 4 + g;
  const int l = gw & (Lc - 1);
  const ushort4 q4 = *reinterpret_cast<const ushort4*>(&Q[((size_t)gw << 6) + (lg << 2)]);
  const float qx = bf2f(q4.x), qy = bf2f(q4.y), qz = bf2f(q4.z), qw = bf2f(q4.w);
  const ushort_t* Kbase = K + ((size_t)bh << 17);  // bh * L * D
  const int* sp = sidx + l * Uc;
  float mx = -1e30f, sm = 0.f;
#pragma unroll 4
  for (int u = 0; u < Uc; ++u) {
    const int idx = sp[u];
    const ushort4 k4 = *reinterpret_cast<const ushort4*>(&Kbase[((size_t)idx << 6) + (lg << 2)]);
    float d = qx * bf2f(k4.x) + qy * bf2f(k4.y) + qz * bf2f(k4.z) + qw * bf2f(k4.w);
#pragma unroll
    for (int off = 8; off > 0; off >>= 1) d += __shfl_xor(d, off);
    mx = fmaxf(mx, d);
    sm += d;
  }
  if (lg == 0) Mout[gw] = mx - sm * (1.f / Uc);
}

// Exact stable top-k via rank counting; grid = 32 bh * 8 chunks, 1 cand/thread.
__global__ __launch_bounds__(256) void topk_kernel(const float* __restrict__ Min,
                                                   int* __restrict__ Mtop) {
  __shared__ float sm[Lc];
  const int bh = blockIdx.x >> 3, chunk = blockIdx.x & 7;
  const int tid = threadIdx.x;
  for (int i = tid; i < Lc; i += 256) sm[i] = Min[bh * Lc + i];
  __syncthreads();
  const int cand = (chunk << 8) + tid;
  const float mv = sm[cand];
  int rank = 0;
  for (int j = 0; j < Lc; j += 4) {
    float4 w4 = *reinterpret_cast<const float4*>(&sm[j]);
    rank += (w4.x > mv || (w4.x == mv && (j + 0) < cand));
    rank += (w4.y > mv || (w4.y == mv && (j + 1) < cand));
    rank += (w4.z > mv || (w4.z == mv && (j + 2) < cand));
    rank += (w4.w > mv || (w4.w == mv && (j + 3) < cand));
  }
  if (rank < Uc) Mtop[bh * Uc + rank] = cand;
}

// ---------------------------------------------------------------------------
// MFMA flash attention: block = (bh, chunk of 128 keys). bf16 K/V read ONCE.
// ---------------------------------------------------------------------------
__global__ __launch_bounds__(256, 3) void attn_flash(
    const ushort_t* __restrict__ Q, const ushort_t* __restrict__ K,
    const ushort_t* __restrict__ V, const int* __restrict__ Mtop,
    float* __restrict__ m_p, float* __restrict__ l_p, float* __restrict__ o_p) {
  __shared__ __align__(16) ushort_t Qs[48 * 80];    // 7680 B, row stride 80
  __shared__ __align__(16) ushort_t KVs[128 * 80];  // 20480 B; Vt[64][144] overlays
  __shared__ __align__(16) ushort_t Ps[48 * 144];   // 13824 B, row stride 144
  __shared__ float mw[4][48];
  __shared__ float lw[4][48];
  const int tid = threadIdx.x;
  const int lane = tid & 63, w = tid >> 6;
  const int cc = lane & 15, hi = lane >> 4;
  const int bh = blockIdx.x >> 4, chunk = blockIdx.x & 15;
  const int kk0 = chunk << 7;
  const ushort_t* Qb = Q + ((size_t)bh << 17);
  const ushort_t* Kb = K + ((size_t)bh << 17);
  const ushort_t* Vb = V + ((size_t)bh << 17);

  // stage Qs (gathered selected rows; rows >= Uc zeroed) and Ks
  for (int i = tid; i < 48 * 8; i += 256) {
    const int r = i >> 3, c8 = (i & 7) << 3;
    bf16x8 v = 0;
    if (r < Uc) {
      const int lsel = Mtop[bh * Uc + r];
      v = *reinterpret_cast<const bf16x8*>(&Qb[((size_t)lsel << 6) + c8]);
    }
    *reinterpret_cast<bf16x8*>(&Qs[r * 80 + c8]) = v;
  }
  for (int i = tid; i < 128 * 8; i += 256) {
    const int r = i >> 3, c8 = (i & 7) << 3;
    *reinterpret_cast<bf16x8*>(&KVs[r * 80 + c8]) =
        *reinterpret_cast<const bf16x8*>(&Kb[((size_t)(kk0 + r) << 6) + c8]);
  }
  __syncthreads();

  // S slice: wave w covers cols [w*32, w*32+32), K-dim 64 = 2 ksteps
  f32x4 sacc[3][2] = {};
#pragma unroll
  for (int s = 0; s < 2; ++s) {
    bf16x8 af[3], bk[2];
#pragma unroll
    for (int i = 0; i < 3; ++i)
      af[i] = *reinterpret_cast<const bf16x8*>(&Qs[(i * 16 + cc) * 80 + s * 32 + hi * 8]);
#pragma unroll
    for (int jj = 0; jj < 2; ++jj)
      bk[jj] = *reinterpret_cast<const bf16x8*>(&KVs[(w * 32 + jj * 16 + cc) * 80 + s * 32 + hi * 8]);
#pragma unroll
    for (int i = 0; i < 3; ++i)
#pragma unroll
      for (int jj = 0; jj < 2; ++jj)
        sacc[i][jj] = __builtin_amdgcn_mfma_f32_16x16x32_bf16(af[i], bk[jj], sacc[i][jj], 0, 0, 0);
  }

  // per-wave row max (scaled)
  float mx[3][4];
#pragma unroll
  for (int i = 0; i < 3; ++i)
#pragma unroll
    for (int r = 0; r < 4; ++r)
      mx[i][r] = fmaxf(sacc[i][0][r], sacc[i][1][r]) * 0.125f;
#pragma unroll
  for (int off = 1; off < 16; off <<= 1)
#pragma unroll
    for (int i = 0; i < 3; ++i)
#pragma unroll
      for (int r = 0; r < 4; ++r)
        mx[i][r] = fmaxf(mx[i][r], __shfl_xor(mx[i][r], off));
  if (cc == 0)
#pragma unroll
    for (int i = 0; i < 3; ++i)
#pragma unroll
      for (int r = 0; r < 4; ++r) mw[w][i * 16 + (hi << 2) + r] = mx[i][r];
  __syncthreads();  // also: all MFMA reads of KVs done -> Vt overlay safe

  // final chunk max; p = exp(s*scale - m); Ps bf16; l partials
  float fm[3][4], ls[3][4];
#pragma unroll
  for (int i = 0; i < 3; ++i)
#pragma unroll
    for (int r = 0; r < 4; ++r) {
      const int row = i * 16 + (hi << 2) + r;
      fm[i][r] = fmaxf(fmaxf(mw[0][row], mw[1][row]), fmaxf(mw[2][row], mw[3][row]));
      ls[i][r] = 0.f;
    }
#pragma unroll
  for (int i = 0; i < 3; ++i)
#pragma unroll
    for (int jj = 0; jj < 2; ++jj)
#pragma unroll
      for (int r = 0; r < 4; ++r) {
        float p = __expf(sacc[i][jj][r] * 0.125f - fm[i][r]);
        ls[i][r] += p;
        Ps[(i * 16 + (hi << 2) + r) * 144 + w * 32 + jj * 16 + cc] = f2bf(p);
      }
#pragma unroll
  for (int off = 1; off < 16; off <<= 1)
#pragma unroll
    for (int i = 0; i < 3; ++i)
#pragma unroll
      for (int r = 0; r < 4; ++r) ls[i][r] += __shfl_xor(ls[i][r], off);
  if (cc == 0)
#pragma unroll
    for (int i = 0; i < 3; ++i)
#pragma unroll
      for (int r = 0; r < 4; ++r) lw[w][i * 16 + (hi << 2) + r] = ls[i][r];

  // stage V transposed over dead K: Vt[d][k], row stride 144 bf16
  {
    ushort_t* Vt = KVs;
    for (int i = tid; i < 128 * 8; i += 256) {
      const int k = i >> 3, c8 = (i & 7) << 3;
      bf16x8 v = *reinterpret_cast<const bf16x8*>(&Vb[((size_t)(kk0 + k) << 6) + c8]);
#pragma unroll
      for (int jq = 0; jq < 8; ++jq) Vt[(c8 + jq) * 144 + k] = (ushort_t)v[jq];
    }
  }
  __syncthreads();

  // PV: wave w covers out cols [w*16, w*16+16); K-dim 128 = 4 ksteps
  f32x4 oacc[3] = {};
#pragma unroll
  for (int s = 0; s < 4; ++s) {
    bf16x8 ap[3], bv;
#pragma unroll
    for (int i = 0; i < 3; ++i)
      ap[i] = *reinterpret_cast<const bf16x8*>(&Ps[(i * 16 + cc) * 144 + s * 32 + hi * 8]);
    bv = *reinterpret_cast<const bf16x8*>(&KVs[(w * 16 + cc) * 144 + s * 32 + hi * 8]);
#pragma unroll
    for (int i = 0; i < 3; ++i)
      oacc[i] = __builtin_amdgcn_mfma_f32_16x16x32_bf16(ap[i], bv, oacc[i], 0, 0, 0);
  }
#pragma unroll
  for (int i = 0; i < 3; ++i)
#pragma unroll
    for (int r = 0; r < 4; ++r) {
      const int row = i * 16 + (hi << 2) + r;
      if (row < Uc)
        o_p[((size_t)((bh * Uc + row) * 16 + chunk) << 6) + w * 16 + cc] = oacc[i][r];
    }
  if (w == 0 && cc == 0)
#pragma unroll
    for (int i = 0; i < 3; ++i)
#pragma unroll
      for (int r = 0; r < 4; ++r) {
        const int row = i * 16 + (hi << 2) + r;
        if (row < Uc) {
          m_p[(bh * Uc + row) * 16 + chunk] = fm[i][r];
          l_p[(bh * Uc + row) * 16 + chunk] =
              lw[0][row] + lw[1][row] + lw[2][row] + lw[3][row];
        }
      }
}

// merge 16 chunk partials; write bf16 ctx into CTXb at selected rows
__global__ __launch_bounds__(256) void attn_combine(
    const float* __restrict__ m_p, const float* __restrict__ l_p,
    const float* __restrict__ o_p, const int* __restrict__ Mtop,
    ushort_t* __restrict__ ctxb) {
  const int w = (blockIdx.x * 256 + threadIdx.x) >> 6;  // bh*40+u
  const int lane = threadIdx.x & 63;
  const float* mp = m_p + w * 16;
  const float* lp = l_p + w * 16;
  float M = -1e30f;
#pragma unroll
  for (int c = 0; c < 16; ++c) M = fmaxf(M, mp[c]);
  float denom = 0.f;
  float wgt[16];
#pragma unroll
  for (int c = 0; c < 16; ++c) {
    wgt[c] = __expf(mp[c] - M);
    denom += lp[c] * wgt[c];
  }
  float acc = 0.f;
#pragma unroll
  for (int c = 0; c < 16; ++c)
    acc += o_p[((size_t)w * 16 + c) * 64 + lane] * wgt[c];
  const int bh = w / Uc;
  const int b = bh >> 3, h = bh & 7;
  const int lsel = Mtop[w];
  ctxb[(size_t)(b * Lc + lsel) * DMc + (h << 6) + lane] = f2bf(acc / denom);
}

__global__ __launch_bounds__(64) void vmean_kernel(const ushort_t* __restrict__ V,
                                                   float* __restrict__ vmean) {
  int blk = blockIdx.x;  // B*H*8
  int bh = blk >> 3, c = blk & 7;
  int lane = threadIdx.x;
  float sm = 0.f;
  int lbase = c << 8;
  for (int l = lbase; l < lbase + 256; ++l)
    sm += bf2f(V[((size_t)(bh * Lc + l) << 6) + lane]);
  atomicAdd(&vmean[(bh << 6) + lane], sm * (1.f / Lc));
}

// ctxb[b,l,h*64+d] = bf16(vmean[b*512 + (h*64+d)])
__global__ __launch_bounds__(256) void build_ctx_kernel(const float* __restrict__ vmean,
                                                        ushort_t* __restrict__ ctxb) {
  int idx = blockIdx.x * 256 + threadIdx.x;
  ctxb[idx] = f2bf(vmean[((idx >> 20) << 9) + (idx & 511)]);
}

// out = LayerNorm(resid + yin) * g + b ; optional bf16 copy. In-place safe.
__global__ __launch_bounds__(256) void add_ln_kernel(
    const float* __restrict__ resid, const float* __restrict__ yin,
    const float* __restrict__ g, const float* __restrict__ bbias,
    float* __restrict__ out, ushort_t* __restrict__ outb) {
  __shared__ float vals[DMc];
  __shared__ float red[4];
  int row = blockIdx.x, tid = threadIdx.x;
  size_t base = (size_t)row * DMc;
  float lsum = 0.f;
  for (int c = tid; c < DMc; c += 256) {
    float t = resid[base + c] + yin[base + c];
    vals[c] = t;
    lsum += t;
  }
  lsum = wave_sum(lsum);
  if ((tid & 63) == 0) red[tid >> 6] = lsum;
  __syncthreads();
  float mean = (red[0] + red[1] + red[2] + red[3]) * (1.f / DMc);
  __syncthreads();
  float lv = 0.f;
  for (int c = tid; c < DMc; c += 256) {
    float dv = vals[c] - mean;
    lv += dv * dv;
  }
  lv = wave_sum(lv);
  if ((tid & 63) == 0) red[tid >> 6] = lv;
  __syncthreads();
  float inv = rsqrtf((red[0] + red[1] + red[2] + red[3]) * (1.f / DMc) + 1e-5f);
  for (int c = tid; c < DMc; c += 256) {
    float o = (vals[c] - mean) * inv * g[c] + bbias[c];
    out[base + c] = o;
    if (outb) outb[base + c] = f2bf(o);
  }
}

extern "C" void kernel_launch(void* const* d_in, const int* in_sizes, int n_in,
                              void* d_out, int out_size, void* d_ws, size_t ws_size,
                              hipStream_t stream) {
  (void)in_sizes; (void)n_in; (void)out_size; (void)ws_size;
  const float* x   = (const float*)d_in[0];
  const float* Wq  = (const float*)d_in[1];
  const float* bq  = (const float*)d_in[2];
  const float* Wk  = (const float*)d_in[3];
  const float* bk  = (const float*)d_in[4];
  const float* Wv  = (const float*)d_in[5];
  const float* bv  = (const float*)d_in[6];
  const float* Wo  = (const float*)d_in[7];
  const float* bo  = (const float*)d_in[8];
  const float* Wc1 = (const float*)d_in[9];
  const float* bc1 = (const float*)d_in[10];
  const float* Wc2 = (const float*)d_in[11];
  const float* bc2 = (const float*)d_in[12];
  const float* g1  = (const float*)d_in[13];
  const float* b1  = (const float*)d_in[14];
  const float* g2  = (const float*)d_in[15];
  const float* b2  = (const float*)d_in[16];
  const int* sidx  = (const int*)d_in[17];
  float* out = (float*)d_out;

  float* ws = (float*)d_ws;
  // f32-word offsets (Q/K/V now bf16, each 2M words used of their 4M slots)
  ushort_t* Qb   = (ushort_t*)ws;               // bf16 (B,H,L,D) 8MB
  ushort_t* Kb   = (ushort_t*)(ws + 4194304);   // bf16 8MB
  ushort_t* Vb   = (ushort_t*)(ws + 8388608);   // bf16 8MB
  // ws+12582912 .. +16777216: attn partials (early) / X1b bf16 (late)
  float* m_p    = ws + 12582912;            // 20480
  float* l_p    = ws + 12603392;            // 20480
  float* o_p    = ws + 12623872;            // 1,310,720
  float* X1     = ws + 16777216;            // 4M
  ushort_t* xb   = (ushort_t*)(ws + 20971520);  // [8192][512] bf16 (2M words)
  ushort_t* Wqkvt= (ushort_t*)(ws + 23068672);  // [1536][512] bf16
  ushort_t* Wot  = (ushort_t*)(ws + 23461888);  // [512][512] bf16
  ushort_t* Wc1b = (ushort_t*)(ws + 23592960);  // [2048][512] bf16
  ushort_t* Wc2b = (ushort_t*)(ws + 24117248);  // [512][2048] bf16
  float* bqkv   = ws + 24641536;            // 1536
  float* Mb     = ws + 24643072;            // 65536
  float* vmean  = ws + 24708608;            // 2048
  int* Mtop     = (int*)(ws + 24710656);    // 1280
  // aliases (producer runs strictly after last consumer of the dead buffer)
  ushort_t* CTXb = Vb;                          // bf16 [8192][512], after vmean
  ushort_t* X1b  = (ushort_t*)(ws + 12582912);  // bf16 [8192][512], after combine
  ushort_t* Yb   = (ushort_t*)ws;               // bf16 [8192][2048] = Qb+Kb slots, after attn

  dim3 blk(256);
  conv_bf16<<<4096, blk, 0, stream>>>(x, xb);
  tconv<<<dim3(16, 16), blk, 0, stream>>>(Wq, Wqkvt, 512, 512, 0);
  tconv<<<dim3(16, 16), blk, 0, stream>>>(Wk, Wqkvt, 512, 512, 512);
  tconv<<<dim3(16, 16), blk, 0, stream>>>(Wv, Wqkvt, 512, 512, 1024);
  tconv<<<dim3(16, 16), blk, 0, stream>>>(Wo, Wot, 512, 512, 0);
  conv_bf16<<<1024, blk, 0, stream>>>(Wc1, Wc1b);
  conv_bf16<<<1024, blk, 0, stream>>>(Wc2, Wc2b);
  concat_bias<<<6, blk, 0, stream>>>(bq, bk, bv, bqkv);

  gemm_mfma<2><<<dim3(12, 64), blk, 0, stream>>>(xb, Wqkvt, bqkv, nullptr, nullptr,
                                                 Qb, Kb, Vb, NT, 1536, DMc);
  compute_M_kernel<<<4096, blk, 0, stream>>>(Qb, Kb, sidx, Mb);
  topk_kernel<<<256, blk, 0, stream>>>(Mb, Mtop);
  attn_flash<<<512, blk, 0, stream>>>(Qb, Kb, Vb, Mtop, m_p, l_p, o_p);
  hipMemsetAsync(vmean, 0, Bc * Hc * Dc * sizeof(float), stream);
  vmean_kernel<<<Bc * Hc * 8, dim3(64), 0, stream>>>(Vb, vmean);
  build_ctx_kernel<<<16384, blk, 0, stream>>>(vmean, CTXb);
  attn_combine<<<320, blk, 0, stream>>>(m_p, l_p, o_p, Mtop, CTXb);

  gemm_mfma<0><<<dim3(4, 64), blk, 0, stream>>>(CTXb, Wot, bo, out, nullptr,
                                                nullptr, nullptr, nullptr,
                                                NT, DMc, DMc);
  add_ln_kernel<<<NT, blk, 0, stream>>>(x, out, g1, b1, X1, X1b);
  gemm_mfma<1><<<dim3(16, 64), blk, 0, stream>>>(X1b, Wc1b, bc1, nullptr, Yb,
                                                 nullptr, nullptr, nullptr,
                                                 NT, DFFc, DMc);
  gemm_mfma<0><<<dim3(4, 64), blk, 0, stream>>>(Yb, Wc2b, bc2, out, nullptr,
                                                nullptr, nullptr, nullptr,
                                                NT, DMc, DFFc);
  add_ln_kernel<<<NT, blk, 0, stream>>>(X1, out, g2, b2, out, nullptr);
}

// Round 11
// 356.766 us; speedup vs baseline: 5.1091x; 1.0707x over previous
//
#include <hip/hip_runtime.h>
#include <math.h>

static constexpr int Bc = 4, Lc = 2048, DMc = 512, Hc = 8, Dc = 64, DFFc = 2048, Uc = 40;
static constexpr int NT = Bc * Lc; // 8192 tokens

typedef __attribute__((ext_vector_type(4))) float f32x4;
typedef __attribute__((ext_vector_type(8))) short bf16x8;
typedef unsigned short ushort_t;

__device__ __forceinline__ float wave_sum(float v) {
#pragma unroll
  for (int off = 32; off > 0; off >>= 1) v += __shfl_xor(v, off);
  return v;
}

__device__ __forceinline__ ushort_t f2bf(float f) {
  union { float f; unsigned int u; } c{f};
  unsigned int u = c.u + 0x7fff + ((c.u >> 16) & 1);
  return (ushort_t)(u >> 16);
}

__device__ __forceinline__ float bf2f(ushort_t b) {
  union { unsigned int u; float f; } c{(unsigned int)b << 16};
  return c.f;
}

__device__ __forceinline__ void gload16(const ushort_t* g, ushort_t* l) {
  __builtin_amdgcn_global_load_lds(
      (const __attribute__((address_space(1))) unsigned int*)g,
      (__attribute__((address_space(3))) unsigned int*)l, 16, 0, 0);
}

// ---------------------------------------------------------------------------
// bf16 MFMA GEMM, 128x128 tile, BK=32, 4 waves, m97 structure + XCD swizzle.
// MODE 0: Cf f32. MODE 1: Cb bf16 relu. MODE 2: QKV scatter -> bf16 (B,H,L,D).
// ---------------------------------------------------------------------------
template <int MODE>
__global__ __launch_bounds__(256) void gemm_mfma(
    const ushort_t* __restrict__ A, const ushort_t* __restrict__ Bt,
    const float* __restrict__ bias, float* __restrict__ Cf,
    ushort_t* __restrict__ Cb, ushort_t* __restrict__ Qo, ushort_t* __restrict__ Ko,
    ushort_t* __restrict__ Vo, int M, int N, int K) {
  __shared__ __align__(16) ushort_t As[128 * 32];
  __shared__ __align__(16) ushort_t Bs[128 * 32];
  const int tid = threadIdx.x;
  const int lane = tid & 63, wave = tid >> 6;
  // XCD-aware bijective swizzle (nwg % 8 == 0 for all our grids)
  const int nwg = gridDim.x * gridDim.y;
  const int lin = blockIdx.y * gridDim.x + blockIdx.x;
  const int swz = (lin & 7) * (nwg >> 3) + (lin >> 3);
  const int m0 = (swz / gridDim.x) << 7, n0 = (swz % gridDim.x) << 7;
  const int wm = ((wave >> 1) << 6), wn = ((wave & 1) << 6);
  f32x4 acc[4][4] = {};
  const ushort_t* aSrc = A + (size_t)(m0 + (tid >> 2)) * K + ((tid & 3) << 3);
  const ushort_t* bSrc = Bt + (size_t)(n0 + (tid >> 2)) * K + ((tid & 3) << 3);
  ushort_t* aDst = As + wave * 512;  // wave-uniform LDS base; HW adds lane*16B
  ushort_t* bDst = Bs + wave * 512;
  const size_t aHalf = (size_t)64 * K, bHalf = (size_t)64 * K;
  for (int k0 = 0; k0 < K; k0 += 32) {
    gload16(aSrc + k0, aDst);
    gload16(aSrc + aHalf + k0, aDst + 2048);
    gload16(bSrc + k0, bDst);
    gload16(bSrc + bHalf + k0, bDst + 2048);
    __syncthreads();  // compiler drains vmcnt before s_barrier -> data ready
    bf16x8 af[4], bfr[4];
    const int fr = lane & 15, ko = (lane >> 4) << 3;
#pragma unroll
    for (int i = 0; i < 4; ++i) {
      af[i] = *reinterpret_cast<const bf16x8*>(&As[(wm + i * 16 + fr) * 32 + ko]);
      bfr[i] = *reinterpret_cast<const bf16x8*>(&Bs[(wn + i * 16 + fr) * 32 + ko]);
    }
#pragma unroll
    for (int i = 0; i < 4; ++i)
#pragma unroll
      for (int j = 0; j < 4; ++j)
        acc[i][j] = __builtin_amdgcn_mfma_f32_16x16x32_bf16(af[i], bfr[j], acc[i][j], 0, 0, 0);
    __syncthreads();
  }
  const int cr = (lane >> 4) << 2, cc = lane & 15;
#pragma unroll
  for (int j = 0; j < 4; ++j) {
    const int col = n0 + wn + j * 16 + cc;
    const float bsv = bias[col];
#pragma unroll
    for (int i = 0; i < 4; ++i) {
#pragma unroll
      for (int r = 0; r < 4; ++r) {
        const int row = m0 + wm + i * 16 + cr + r;
        float v = acc[i][j][r] + bsv;
        if (MODE == 0) {
          Cf[(size_t)row * N + col] = v;
        } else if (MODE == 1) {
          Cb[(size_t)row * N + col] = f2bf(fmaxf(v, 0.f));
        } else {
          const int which = col >> 9, h = (col >> 6) & 7, d = col & 63;
          const int b = row >> 11, l = row & (Lc - 1);
          const size_t o = ((size_t)(((b << 3) + h) << 11) + l) * 64 + d;
          ushort_t* dst = which == 0 ? Qo : (which == 1 ? Ko : Vo);
          dst[o] = f2bf(v);
        }
      }
    }
  }
}

// f32 -> bf16 elementwise (n multiple of 1024; grid = n/1024)
__global__ __launch_bounds__(256) void conv_bf16(const float* __restrict__ in,
                                                 ushort_t* __restrict__ out) {
  int i = blockIdx.x * 256 + threadIdx.x;
  float4 v = *reinterpret_cast<const float4*>(&in[(size_t)i * 4]);
  ushort4 o;
  o.x = f2bf(v.x); o.y = f2bf(v.y); o.z = f2bf(v.z); o.w = f2bf(v.w);
  *reinterpret_cast<ushort4*>(&out[(size_t)i * 4]) = o;
}

// transpose-convert: in f32 [R][C] -> out bf16 rows [rowOff + c][r], row stride R
__global__ __launch_bounds__(256) void tconv(const float* __restrict__ in,
                                             ushort_t* __restrict__ out,
                                             int R, int C, int rowOff) {
  __shared__ float t[32][33];
  const int r0 = blockIdx.y << 5, c0 = blockIdx.x << 5;
  const int tr = threadIdx.x >> 5, tc = threadIdx.x & 31;
#pragma unroll
  for (int p = 0; p < 4; ++p)
    t[tr + p * 8][tc] = in[(size_t)(r0 + tr + p * 8) * C + c0 + tc];
  __syncthreads();
#pragma unroll
  for (int p = 0; p < 4; ++p)
    out[(size_t)(rowOff + c0 + tr + p * 8) * R + r0 + tc] = f2bf(t[tc][tr + p * 8]);
}

__global__ __launch_bounds__(256) void concat_bias(const float* __restrict__ bq,
                                                   const float* __restrict__ bk,
                                                   const float* __restrict__ bv,
                                                   float* __restrict__ o) {
  int i = blockIdx.x * 256 + threadIdx.x;
  o[i] = i < 512 ? bq[i] : (i < 1024 ? bk[i - 512] : bv[i - 1024]);
}

// M[b,h,l] = max_u(q.k_su) - mean_u(q.k_su); 16-lane group per (b,h,l).
// bf16 Q/K; XCD-grouped: all 128 blocks of one bh land on one XCD.
__global__ __launch_bounds__(256) void compute_M_kernel(
    const ushort_t* __restrict__ Q, const ushort_t* __restrict__ K,
    const int* __restrict__ sidx, float* __restrict__ Mout) {
  const int tid = threadIdx.x;
  const int wave = tid >> 6, lane = tid & 63;
  const int g = lane >> 4, lg = lane & 15;
  const int p = blockIdx.x;                 // 4096
  const int xcd = p & 7, j = p >> 3;        // j: 0..511
  const int bh = xcd + ((j >> 7) << 3);     // 4 bh per XCD
  const int inner = j & 127;
  const int gw = (bh << 11) + (inner << 4) + wave * 4 + g;
  const int l = gw & (Lc - 1);
  const ushort4 q4 = *reinterpret_cast<const ushort4*>(&Q[((size_t)gw << 6) + (lg << 2)]);
  const float qx = bf2f(q4.x), qy = bf2f(q4.y), qz = bf2f(q4.z), qw = bf2f(q4.w);
  const ushort_t* Kbase = K + ((size_t)bh << 17);  // bh * L * D
  const int* sp = sidx + l * Uc;
  float mx = -1e30f, sm = 0.f;
#pragma unroll 4
  for (int u = 0; u < Uc; ++u) {
    const int idx = sp[u];
    const ushort4 k4 = *reinterpret_cast<const ushort4*>(&Kbase[((size_t)idx << 6) + (lg << 2)]);
    float d = qx * bf2f(k4.x) + qy * bf2f(k4.y) + qz * bf2f(k4.z) + qw * bf2f(k4.w);
#pragma unroll
    for (int off = 8; off > 0; off >>= 1) d += __shfl_xor(d, off);
    mx = fmaxf(mx, d);
    sm += d;
  }
  if (lg == 0) Mout[gw] = mx - sm * (1.f / Uc);
}

// ---------------------------------------------------------------------------
// Exact top-k via threshold screen: block per bh. Binary-search the 40th
// largest (sortable-uint domain), then exact rank-count the ~40 survivors.
// ---------------------------------------------------------------------------
__global__ __launch_bounds__(256) void topk_kernel(const float* __restrict__ Min,
                                                   int* __restrict__ Mtop) {
  __shared__ unsigned sm[Lc];   // sortable-uint copies
  __shared__ int scount[4];
  __shared__ int slist[Lc];
  __shared__ int snum;
  const int bh = blockIdx.x;
  const int tid = threadIdx.x;
  const int wv = tid >> 6, lane = tid & 63;
  unsigned sv[8];
#pragma unroll
  for (int t = 0; t < 8; ++t) {
    const unsigned u = __float_as_uint(Min[bh * Lc + tid + (t << 8)]);
    const unsigned s = (u & 0x80000000u) ? ~u : (u | 0x80000000u);
    sv[t] = s;
    sm[tid + (t << 8)] = s;
  }
  if (tid == 0) snum = 0;
  __syncthreads();
  // binary search: largest thr with count(sv >= thr) >= Uc  (== 40th largest)
  unsigned lo = 0u, hi = 0xFFFFFFFFu;
  while (lo < hi) {
    const unsigned mid =
        (unsigned)(((unsigned long long)lo + (unsigned long long)hi + 1ull) >> 1);
    int cnt = 0;
#pragma unroll
    for (int t = 0; t < 8; ++t) cnt += (sv[t] >= mid);
#pragma unroll
    for (int off = 32; off > 0; off >>= 1) cnt += __shfl_xor(cnt, off);
    if (lane == 0) scount[wv] = cnt;
    __syncthreads();
    const int total = scount[0] + scount[1] + scount[2] + scount[3];
    __syncthreads();
    if (total >= Uc) lo = mid; else hi = mid - 1;
  }
  // collect survivors (every rank<Uc candidate has sv >= lo)
#pragma unroll
  for (int t = 0; t < 8; ++t)
    if (sv[t] >= lo) {
      const int pos = atomicAdd(&snum, 1);
      slist[pos] = tid + (t << 8);
    }
  __syncthreads();
  // exact rank for each survivor; wave-cooperative scan (lane covers 32 elems)
  const int S = snum;
  const int jbase = lane << 5;
  for (int s = wv; s < S; s += 4) {
    const int c = slist[s];
    const unsigned mv = sm[c];
    int rank = 0;
#pragma unroll
    for (int q = 0; q < 8; ++q) {
      const int j = jbase + (q << 2);
      const uint4 w4 = *reinterpret_cast<const uint4*>(&sm[j]);
      rank += (w4.x > mv || (w4.x == mv && (j + 0) < c));
      rank += (w4.y > mv || (w4.y == mv && (j + 1) < c));
      rank += (w4.z > mv || (w4.z == mv && (j + 2) < c));
      rank += (w4.w > mv || (w4.w == mv && (j + 3) < c));
    }
#pragma unroll
    for (int off = 32; off > 0; off >>= 1) rank += __shfl_xor(rank, off);
    if (lane == 0 && rank < Uc) Mtop[bh * Uc + rank] = c;
  }
}

// ---------------------------------------------------------------------------
// MFMA flash attention: block = (bh, chunk of 128 keys). bf16 K/V read ONCE.
// ---------------------------------------------------------------------------
__global__ __launch_bounds__(256, 3) void attn_flash(
    const ushort_t* __restrict__ Q, const ushort_t* __restrict__ K,
    const ushort_t* __restrict__ V, const int* __restrict__ Mtop,
    float* __restrict__ m_p, float* __restrict__ l_p, float* __restrict__ o_p) {
  __shared__ __align__(16) ushort_t Qs[48 * 80];    // 7680 B, row stride 80
  __shared__ __align__(16) ushort_t KVs[128 * 80];  // 20480 B; Vt[64][144] overlays
  __shared__ __align__(16) ushort_t Ps[48 * 144];   // 13824 B, row stride 144
  __shared__ float mw[4][48];
  __shared__ float lw[4][48];
  const int tid = threadIdx.x;
  const int lane = tid & 63, w = tid >> 6;
  const int cc = lane & 15, hi = lane >> 4;
  const int bh = blockIdx.x >> 4, chunk = blockIdx.x & 15;
  const int kk0 = chunk << 7;
  const ushort_t* Qb = Q + ((size_t)bh << 17);
  const ushort_t* Kb = K + ((size_t)bh << 17);
  const ushort_t* Vb = V + ((size_t)bh << 17);

  // stage Qs (gathered selected rows; rows >= Uc zeroed) and Ks
  for (int i = tid; i < 48 * 8; i += 256) {
    const int r = i >> 3, c8 = (i & 7) << 3;
    bf16x8 v = 0;
    if (r < Uc) {
      const int lsel = Mtop[bh * Uc + r];
      v = *reinterpret_cast<const bf16x8*>(&Qb[((size_t)lsel << 6) + c8]);
    }
    *reinterpret_cast<bf16x8*>(&Qs[r * 80 + c8]) = v;
  }
  for (int i = tid; i < 128 * 8; i += 256) {
    const int r = i >> 3, c8 = (i & 7) << 3;
    *reinterpret_cast<bf16x8*>(&KVs[r * 80 + c8]) =
        *reinterpret_cast<const bf16x8*>(&Kb[((size_t)(kk0 + r) << 6) + c8]);
  }
  __syncthreads();

  // S slice: wave w covers cols [w*32, w*32+32), K-dim 64 = 2 ksteps
  f32x4 sacc[3][2] = {};
#pragma unroll
  for (int s = 0; s < 2; ++s) {
    bf16x8 af[3], bk[2];
#pragma unroll
    for (int i = 0; i < 3; ++i)
      af[i] = *reinterpret_cast<const bf16x8*>(&Qs[(i * 16 + cc) * 80 + s * 32 + hi * 8]);
#pragma unroll
    for (int jj = 0; jj < 2; ++jj)
      bk[jj] = *reinterpret_cast<const bf16x8*>(&KVs[(w * 32 + jj * 16 + cc) * 80 + s * 32 + hi * 8]);
#pragma unroll
    for (int i = 0; i < 3; ++i)
#pragma unroll
      for (int jj = 0; jj < 2; ++jj)
        sacc[i][jj] = __builtin_amdgcn_mfma_f32_16x16x32_bf16(af[i], bk[jj], sacc[i][jj], 0, 0, 0);
  }

  // per-wave row max (scaled)
  float mx[3][4];
#pragma unroll
  for (int i = 0; i < 3; ++i)
#pragma unroll
    for (int r = 0; r < 4; ++r)
      mx[i][r] = fmaxf(sacc[i][0][r], sacc[i][1][r]) * 0.125f;
#pragma unroll
  for (int off = 1; off < 16; off <<= 1)
#pragma unroll
    for (int i = 0; i < 3; ++i)
#pragma unroll
      for (int r = 0; r < 4; ++r)
        mx[i][r] = fmaxf(mx[i][r], __shfl_xor(mx[i][r], off));
  if (cc == 0)
#pragma unroll
    for (int i = 0; i < 3; ++i)
#pragma unroll
      for (int r = 0; r < 4; ++r) mw[w][i * 16 + (hi << 2) + r] = mx[i][r];
  __syncthreads();  // also: all MFMA reads of KVs done -> Vt overlay safe

  // final chunk max; p = exp(s*scale - m); Ps bf16; l partials
  float fm[3][4], ls[3][4];
#pragma unroll
  for (int i = 0; i < 3; ++i)
#pragma unroll
    for (int r = 0; r < 4; ++r) {
      const int row = i * 16 + (hi << 2) + r;
      fm[i][r] = fmaxf(fmaxf(mw[0][row], mw[1][row]), fmaxf(mw[2][row], mw[3][row]));
      ls[i][r] = 0.f;
    }
#pragma unroll
  for (int i = 0; i < 3; ++i)
#pragma unroll
    for (int jj = 0; jj < 2; ++jj)
#pragma unroll
      for (int r = 0; r < 4; ++r) {
        float p = __expf(sacc[i][jj][r] * 0.125f - fm[i][r]);
        ls[i][r] += p;
        Ps[(i * 16 + (hi << 2) + r) * 144 + w * 32 + jj * 16 + cc] = f2bf(p);
      }
#pragma unroll
  for (int off = 1; off < 16; off <<= 1)
#pragma unroll
    for (int i = 0; i < 3; ++i)
#pragma unroll
      for (int r = 0; r < 4; ++r) ls[i][r] += __shfl_xor(ls[i][r], off);
  if (cc == 0)
#pragma unroll
    for (int i = 0; i < 3; ++i)
#pragma unroll
      for (int r = 0; r < 4; ++r) lw[w][i * 16 + (hi << 2) + r] = ls[i][r];

  // stage V transposed over dead K: Vt[d][k], row stride 144 bf16
  {
    ushort_t* Vt = KVs;
    for (int i = tid; i < 128 * 8; i += 256) {
      const int k = i >> 3, c8 = (i & 7) << 3;
      bf16x8 v = *reinterpret_cast<const bf16x8*>(&Vb[((size_t)(kk0 + k) << 6) + c8]);
#pragma unroll
      for (int jq = 0; jq < 8; ++jq) Vt[(c8 + jq) * 144 + k] = (ushort_t)v[jq];
    }
  }
  __syncthreads();

  // PV: wave w covers out cols [w*16, w*16+16); K-dim 128 = 4 ksteps
  f32x4 oacc[3] = {};
#pragma unroll
  for (int s = 0; s < 4; ++s) {
    bf16x8 ap[3], bv;
#pragma unroll
    for (int i = 0; i < 3; ++i)
      ap[i] = *reinterpret_cast<const bf16x8*>(&Ps[(i * 16 + cc) * 144 + s * 32 + hi * 8]);
    bv = *reinterpret_cast<const bf16x8*>(&KVs[(w * 16 + cc) * 144 + s * 32 + hi * 8]);
#pragma unroll
    for (int i = 0; i < 3; ++i)
      oacc[i] = __builtin_amdgcn_mfma_f32_16x16x32_bf16(ap[i], bv, oacc[i], 0, 0, 0);
  }
#pragma unroll
  for (int i = 0; i < 3; ++i)
#pragma unroll
    for (int r = 0; r < 4; ++r) {
      const int row = i * 16 + (hi << 2) + r;
      if (row < Uc)
        o_p[((size_t)((bh * Uc + row) * 16 + chunk) << 6) + w * 16 + cc] = oacc[i][r];
    }
  if (w == 0 && cc == 0)
#pragma unroll
    for (int i = 0; i < 3; ++i)
#pragma unroll
      for (int r = 0; r < 4; ++r) {
        const int row = i * 16 + (hi << 2) + r;
        if (row < Uc) {
          m_p[(bh * Uc + row) * 16 + chunk] = fm[i][r];
          l_p[(bh * Uc + row) * 16 + chunk] =
              lw[0][row] + lw[1][row] + lw[2][row] + lw[3][row];
        }
      }
}

// merge 16 chunk partials; write bf16 ctx into CTXb at selected rows
__global__ __launch_bounds__(256) void attn_combine(
    const float* __restrict__ m_p, const float* __restrict__ l_p,
    const float* __restrict__ o_p, const int* __restrict__ Mtop,
    ushort_t* __restrict__ ctxb) {
  const int w = (blockIdx.x * 256 + threadIdx.x) >> 6;  // bh*40+u
  const int lane = threadIdx.x & 63;
  const float* mp = m_p + w * 16;
  const float* lp = l_p + w * 16;
  float M = -1e30f;
#pragma unroll
  for (int c = 0; c < 16; ++c) M = fmaxf(M, mp[c]);
  float denom = 0.f;
  float wgt[16];
#pragma unroll
  for (int c = 0; c < 16; ++c) {
    wgt[c] = __expf(mp[c] - M);
    denom += lp[c] * wgt[c];
  }
  float acc = 0.f;
#pragma unroll
  for (int c = 0; c < 16; ++c)
    acc += o_p[((size_t)w * 16 + c) * 64 + lane] * wgt[c];
  const int bh = w / Uc;
  const int b = bh >> 3, h = bh & 7;
  const int lsel = Mtop[w];
  ctxb[(size_t)(b * Lc + lsel) * DMc + (h << 6) + lane] = f2bf(acc / denom);
}

__global__ __launch_bounds__(64) void vmean_kernel(const ushort_t* __restrict__ V,
                                                   float* __restrict__ vmean) {
  int blk = blockIdx.x;  // B*H*8
  int bh = blk >> 3, c = blk & 7;
  int lane = threadIdx.x;
  float sm = 0.f;
  int lbase = c << 8;
  for (int l = lbase; l < lbase + 256; ++l)
    sm += bf2f(V[((size_t)(bh * Lc + l) << 6) + lane]);
  atomicAdd(&vmean[(bh << 6) + lane], sm * (1.f / Lc));
}

// ctxb[b,l,h*64+d] = bf16(vmean[b*512 + (h*64+d)])
__global__ __launch_bounds__(256) void build_ctx_kernel(const float* __restrict__ vmean,
                                                        ushort_t* __restrict__ ctxb) {
  int idx = blockIdx.x * 256 + threadIdx.x;
  ctxb[idx] = f2bf(vmean[((idx >> 20) << 9) + (idx & 511)]);
}

// out = LayerNorm(resid + yin) * g + b ; optional bf16 copy. In-place safe.
__global__ __launch_bounds__(256) void add_ln_kernel(
    const float* __restrict__ resid, const float* __restrict__ yin,
    const float* __restrict__ g, const float* __restrict__ bbias,
    float* __restrict__ out, ushort_t* __restrict__ outb) {
  __shared__ float vals[DMc];
  __shared__ float red[4];
  int row = blockIdx.x, tid = threadIdx.x;
  size_t base = (size_t)row * DMc;
  float lsum = 0.f;
  for (int c = tid; c < DMc; c += 256) {
    float t = resid[base + c] + yin[base + c];
    vals[c] = t;
    lsum += t;
  }
  lsum = wave_sum(lsum);
  if ((tid & 63) == 0) red[tid >> 6] = lsum;
  __syncthreads();
  float mean = (red[0] + red[1] + red[2] + red[3]) * (1.f / DMc);
  __syncthreads();
  float lv = 0.f;
  for (int c = tid; c < DMc; c += 256) {
    float dv = vals[c] - mean;
    lv += dv * dv;
  }
  lv = wave_sum(lv);
  if ((tid & 63) == 0) red[tid >> 6] = lv;
  __syncthreads();
  float inv = rsqrtf((red[0] + red[1] + red[2] + red[3]) * (1.f / DMc) + 1e-5f);
  for (int c = tid; c < DMc; c += 256) {
    float o = (vals[c] - mean) * inv * g[c] + bbias[c];
    out[base + c] = o;
    if (outb) outb[base + c] = f2bf(o);
  }
}

extern "C" void kernel_launch(void* const* d_in, const int* in_sizes, int n_in,
                              void* d_out, int out_size, void* d_ws, size_t ws_size,
                              hipStream_t stream) {
  (void)in_sizes; (void)n_in; (void)out_size; (void)ws_size;
  const float* x   = (const float*)d_in[0];
  const float* Wq  = (const float*)d_in[1];
  const float* bq  = (const float*)d_in[2];
  const float* Wk  = (const float*)d_in[3];
  const float* bk  = (const float*)d_in[4];
  const float* Wv  = (const float*)d_in[5];
  const float* bv  = (const float*)d_in[6];
  const float* Wo  = (const float*)d_in[7];
  const float* bo  = (const float*)d_in[8];
  const float* Wc1 = (const float*)d_in[9];
  const float* bc1 = (const float*)d_in[10];
  const float* Wc2 = (const float*)d_in[11];
  const float* bc2 = (const float*)d_in[12];
  const float* g1  = (const float*)d_in[13];
  const float* b1  = (const float*)d_in[14];
  const float* g2  = (const float*)d_in[15];
  const float* b2  = (const float*)d_in[16];
  const int* sidx  = (const int*)d_in[17];
  float* out = (float*)d_out;

  float* ws = (float*)d_ws;
  // f32-word offsets (Q/K/V bf16, each 2M words used of their 4M slots)
  ushort_t* Qb   = (ushort_t*)ws;               // bf16 (B,H,L,D) 8MB
  ushort_t* Kb   = (ushort_t*)(ws + 4194304);   // bf16 8MB
  ushort_t* Vb   = (ushort_t*)(ws + 8388608);   // bf16 8MB
  // ws+12582912 .. +16777216: attn partials (early) / X1b bf16 (late)
  float* m_p    = ws + 12582912;            // 20480
  float* l_p    = ws + 12603392;            // 20480
  float* o_p    = ws + 12623872;            // 1,310,720
  float* X1     = ws + 16777216;            // 4M
  ushort_t* xb   = (ushort_t*)(ws + 20971520);  // [8192][512] bf16 (2M words)
  ushort_t* Wqkvt= (ushort_t*)(ws + 23068672);  // [1536][512] bf16
  ushort_t* Wot  = (ushort_t*)(ws + 23461888);  // [512][512] bf16
  ushort_t* Wc1b = (ushort_t*)(ws + 23592960);  // [2048][512] bf16
  ushort_t* Wc2b = (ushort_t*)(ws + 24117248);  // [512][2048] bf16
  float* bqkv   = ws + 24641536;            // 1536
  float* Mb     = ws + 24643072;            // 65536
  float* vmean  = ws + 24708608;            // 2048
  int* Mtop     = (int*)(ws + 24710656);    // 1280
  // aliases (producer runs strictly after last consumer of the dead buffer)
  ushort_t* CTXb = Vb;                          // bf16 [8192][512], after vmean
  ushort_t* X1b  = (ushort_t*)(ws + 12582912);  // bf16 [8192][512], after combine
  ushort_t* Yb   = (ushort_t*)ws;               // bf16 [8192][2048] = Qb+Kb slots, after attn

  dim3 blk(256);
  conv_bf16<<<4096, blk, 0, stream>>>(x, xb);
  tconv<<<dim3(16, 16), blk, 0, stream>>>(Wq, Wqkvt, 512, 512, 0);
  tconv<<<dim3(16, 16), blk, 0, stream>>>(Wk, Wqkvt, 512, 512, 512);
  tconv<<<dim3(16, 16), blk, 0, stream>>>(Wv, Wqkvt, 512, 512, 1024);
  tconv<<<dim3(16, 16), blk, 0, stream>>>(Wo, Wot, 512, 512, 0);
  conv_bf16<<<1024, blk, 0, stream>>>(Wc1, Wc1b);
  conv_bf16<<<1024, blk, 0, stream>>>(Wc2, Wc2b);
  concat_bias<<<6, blk, 0, stream>>>(bq, bk, bv, bqkv);

  gemm_mfma<2><<<dim3(12, 64), blk, 0, stream>>>(xb, Wqkvt, bqkv, nullptr, nullptr,
                                                 Qb, Kb, Vb, NT, 1536, DMc);
  compute_M_kernel<<<4096, blk, 0, stream>>>(Qb, Kb, sidx, Mb);
  topk_kernel<<<32, blk, 0, stream>>>(Mb, Mtop);
  attn_flash<<<512, blk, 0, stream>>>(Qb, Kb, Vb, Mtop, m_p, l_p, o_p);
  hipMemsetAsync(vmean, 0, Bc * Hc * Dc * sizeof(float), stream);
  vmean_kernel<<<Bc * Hc * 8, dim3(64), 0, stream>>>(Vb, vmean);
  build_ctx_kernel<<<16384, blk, 0, stream>>>(vmean, CTXb);
  attn_combine<<<320, blk, 0, stream>>>(m_p, l_p, o_p, Mtop, CTXb);

  gemm_mfma<0><<<dim3(4, 64), blk, 0, stream>>>(CTXb, Wot, bo, out, nullptr,
                                                nullptr, nullptr, nullptr,
                                                NT, DMc, DMc);
  add_ln_kernel<<<NT, blk, 0, stream>>>(x, out, g1, b1, X1, X1b);
  gemm_mfma<1><<<dim3(16, 64), blk, 0, stream>>>(X1b, Wc1b, bc1, nullptr, Yb,
                                                 nullptr, nullptr, nullptr,
                                                 NT, DFFc, DMc);
  gemm_mfma<0><<<dim3(4, 64), blk, 0, stream>>>(Yb, Wc2b, bc2, out, nullptr,
                                                nullptr, nullptr, nullptr,
                                                NT, DMc, DFFc);
  add_ln_kernel<<<NT, blk, 0, stream>>>(X1, out, g2, b2, out, nullptr);
}

// Round 13
// 327.730 us; speedup vs baseline: 5.5618x; 1.0886x over previous
//
#include <hip/hip_runtime.h>
#include <math.h>

static constexpr int Bc = 4, Lc = 2048, DMc = 512, Hc = 8, Dc = 64, DFFc = 2048, Uc = 40;
static constexpr int NT = Bc * Lc; // 8192 tokens

typedef __attribute__((ext_vector_type(4))) float f32x4;
typedef __attribute__((ext_vector_type(8))) short bf16x8;
typedef unsigned short ushort_t;

__device__ __forceinline__ float wave_sum(float v) {
#pragma unroll
  for (int off = 32; off > 0; off >>= 1) v += __shfl_xor(v, off);
  return v;
}

__device__ __forceinline__ ushort_t f2bf(float f) {
  union { float f; unsigned int u; } c{f};
  unsigned int u = c.u + 0x7fff + ((c.u >> 16) & 1);
  return (ushort_t)(u >> 16);
}

__device__ __forceinline__ float bf2f(ushort_t b) {
  union { unsigned int u; float f; } c{(unsigned int)b << 16};
  return c.f;
}

__device__ __forceinline__ void gload16(const ushort_t* g, ushort_t* l) {
  __builtin_amdgcn_global_load_lds(
      (const __attribute__((address_space(1))) unsigned int*)g,
      (__attribute__((address_space(3))) unsigned int*)l, 16, 0, 0);
}

// ---------------------------------------------------------------------------
// bf16 MFMA GEMM, 128x128 tile, BK=32, 4 waves, m97 structure + XCD swizzle.
// MODE 0: Cf f32. MODE 1: Cb bf16 relu. MODE 2: QKV scatter -> bf16 (B,H,L,D).
// MODE 3: split-K=2 (grid dim3(4,128); gy&63 = m-tile, gy>>6 = K-half):
//         half 0 -> Cf (+bias), half 1 -> Cf1 (no bias). Kh = K/2.
// ---------------------------------------------------------------------------
template <int MODE>
__global__ __launch_bounds__(256) void gemm_mfma(
    const ushort_t* __restrict__ A, const ushort_t* __restrict__ Bt,
    const float* __restrict__ bias, float* __restrict__ Cf,
    float* __restrict__ Cf1, ushort_t* __restrict__ Cb,
    ushort_t* __restrict__ Qo, ushort_t* __restrict__ Ko,
    ushort_t* __restrict__ Vo, int M, int N, int K, int Kh) {
  __shared__ __align__(16) ushort_t As[128 * 32];
  __shared__ __align__(16) ushort_t Bs[128 * 32];
  const int tid = threadIdx.x;
  const int lane = tid & 63, wave = tid >> 6;
  // XCD-aware bijective swizzle (nwg % 8 == 0 for all our grids)
  const int nwg = gridDim.x * gridDim.y;
  const int lin = blockIdx.y * gridDim.x + blockIdx.x;
  const int swz = (lin & 7) * (nwg >> 3) + (lin >> 3);
  int m0, n0, kpart = 0;
  if (MODE == 3) {
    const int gy = swz / gridDim.x;
    n0 = (swz % gridDim.x) << 7;
    m0 = (gy & 63) << 7;
    kpart = gy >> 6;
  } else {
    m0 = (swz / gridDim.x) << 7;
    n0 = (swz % gridDim.x) << 7;
  }
  const int kOff = kpart * Kh;
  const int wm = ((wave >> 1) << 6), wn = ((wave & 1) << 6);
  f32x4 acc[4][4] = {};
  const ushort_t* aSrc = A + (size_t)(m0 + (tid >> 2)) * K + ((tid & 3) << 3) + kOff;
  const ushort_t* bSrc = Bt + (size_t)(n0 + (tid >> 2)) * K + ((tid & 3) << 3) + kOff;
  ushort_t* aDst = As + wave * 512;  // wave-uniform LDS base; HW adds lane*16B
  ushort_t* bDst = Bs + wave * 512;
  const size_t aHalf = (size_t)64 * K, bHalf = (size_t)64 * K;
  for (int k0 = 0; k0 < Kh; k0 += 32) {
    gload16(aSrc + k0, aDst);
    gload16(aSrc + aHalf + k0, aDst + 2048);
    gload16(bSrc + k0, bDst);
    gload16(bSrc + bHalf + k0, bDst + 2048);
    __syncthreads();  // compiler drains vmcnt before s_barrier -> data ready
    bf16x8 af[4], bfr[4];
    const int fr = lane & 15, ko = (lane >> 4) << 3;
#pragma unroll
    for (int i = 0; i < 4; ++i) {
      af[i] = *reinterpret_cast<const bf16x8*>(&As[(wm + i * 16 + fr) * 32 + ko]);
      bfr[i] = *reinterpret_cast<const bf16x8*>(&Bs[(wn + i * 16 + fr) * 32 + ko]);
    }
#pragma unroll
    for (int i = 0; i < 4; ++i)
#pragma unroll
      for (int j = 0; j < 4; ++j)
        acc[i][j] = __builtin_amdgcn_mfma_f32_16x16x32_bf16(af[i], bfr[j], acc[i][j], 0, 0, 0);
    __syncthreads();
  }
  const int cr = (lane >> 4) << 2, cc = lane & 15;
#pragma unroll
  for (int j = 0; j < 4; ++j) {
    const int col = n0 + wn + j * 16 + cc;
    const float bsv = bias[col];
#pragma unroll
    for (int i = 0; i < 4; ++i) {
#pragma unroll
      for (int r = 0; r < 4; ++r) {
        const int row = m0 + wm + i * 16 + cr + r;
        float v = acc[i][j][r];
        if (MODE == 0) {
          Cf[(size_t)row * N + col] = v + bsv;
        } else if (MODE == 1) {
          Cb[(size_t)row * N + col] = f2bf(fmaxf(v + bsv, 0.f));
        } else if (MODE == 3) {
          float* dstf = kpart ? Cf1 : Cf;
          dstf[(size_t)row * N + col] = kpart ? v : v + bsv;
        } else {
          v += bsv;
          const int which = col >> 9, h = (col >> 6) & 7, d = col & 63;
          const int b = row >> 11, l = row & (Lc - 1);
          const size_t o = ((size_t)(((b << 3) + h) << 11) + l) * 64 + d;
          ushort_t* dst = which == 0 ? Qo : (which == 1 ? Ko : Vo);
          dst[o] = f2bf(v);
        }
      }
    }
  }
}

// ---------------------------------------------------------------------------
// Fused prologue: x->bf16 (blk 0..4095), Wq/Wk/Wv/Wo transpose-convert
// (blk 4096..5119, 256 blocks each), Wc1/Wc2 convert (5120..7167),
// bias concat (7168..7173). Grid = 7174.
// ---------------------------------------------------------------------------
__global__ __launch_bounds__(256) void prep_kernel(
    const float* __restrict__ x, const float* __restrict__ Wq,
    const float* __restrict__ Wk, const float* __restrict__ Wv,
    const float* __restrict__ Wo, const float* __restrict__ Wc1,
    const float* __restrict__ Wc2, const float* __restrict__ bq,
    const float* __restrict__ bk, const float* __restrict__ bv,
    ushort_t* __restrict__ xb, ushort_t* __restrict__ Wqkvt,
    ushort_t* __restrict__ Wot, ushort_t* __restrict__ Wc1b,
    ushort_t* __restrict__ Wc2b, float* __restrict__ bqkv) {
  __shared__ float t[32][33];
  const int blk = blockIdx.x, tid = threadIdx.x;
  if (blk < 4096) {
    const int i = blk * 256 + tid;
    float4 v = *reinterpret_cast<const float4*>(&x[(size_t)i * 4]);
    ushort4 o;
    o.x = f2bf(v.x); o.y = f2bf(v.y); o.z = f2bf(v.z); o.w = f2bf(v.w);
    *reinterpret_cast<ushort4*>(&xb[(size_t)i * 4]) = o;
  } else if (blk < 5120) {
    const int wsel = (blk - 4096) >> 8, tt = (blk - 4096) & 255;  // 256 blk/matrix
    const float* src = wsel == 0 ? Wq : (wsel == 1 ? Wk : (wsel == 2 ? Wv : Wo));
    ushort_t* dst = wsel == 3 ? Wot : Wqkvt;
    const int rowOff = wsel == 1 ? 512 : (wsel == 2 ? 1024 : 0);
    const int r0 = (tt >> 4) << 5, c0 = (tt & 15) << 5;  // both < 512
    const int tr = tid >> 5, tc = tid & 31;
#pragma unroll
    for (int p = 0; p < 4; ++p)
      t[tr + p * 8][tc] = src[(size_t)(r0 + tr + p * 8) * 512 + c0 + tc];
    __syncthreads();
#pragma unroll
    for (int p = 0; p < 4; ++p)
      dst[(size_t)(rowOff + c0 + tr + p * 8) * 512 + r0 + tc] = f2bf(t[tc][tr + p * 8]);
  } else if (blk < 7168) {
    const int which = (blk - 5120) >> 10;
    const int i = ((blk - 5120) & 1023) * 256 + tid;
    const float* src = which == 0 ? Wc1 : Wc2;
    ushort_t* dst = which == 0 ? Wc1b : Wc2b;
    float4 v = *reinterpret_cast<const float4*>(&src[(size_t)i * 4]);
    ushort4 o;
    o.x = f2bf(v.x); o.y = f2bf(v.y); o.z = f2bf(v.z); o.w = f2bf(v.w);
    *reinterpret_cast<ushort4*>(&dst[(size_t)i * 4]) = o;
  } else {
    const int i = (blk - 7168) * 256 + tid;
    bqkv[i] = i < 512 ? bq[i] : (i < 1024 ? bk[i - 512] : bv[i - 1024]);
  }
}

// M[b,h,l] = max_u(q.k_su) - mean_u(q.k_su); 16-lane group per (b,h,l).
// bf16 Q/K; XCD-grouped: all 128 blocks of one bh land on one XCD.
__global__ __launch_bounds__(256) void compute_M_kernel(
    const ushort_t* __restrict__ Q, const ushort_t* __restrict__ K,
    const int* __restrict__ sidx, float* __restrict__ Mout) {
  const int tid = threadIdx.x;
  const int wave = tid >> 6, lane = tid & 63;
  const int g = lane >> 4, lg = lane & 15;
  const int p = blockIdx.x;                 // 4096
  const int xcd = p & 7, j = p >> 3;        // j: 0..511
  const int bh = xcd + ((j >> 7) << 3);     // 4 bh per XCD
  const int inner = j & 127;
  const int gw = (bh << 11) + (inner << 4) + wave * 4 + g;
  const int l = gw & (Lc - 1);
  const ushort4 q4 = *reinterpret_cast<const ushort4*>(&Q[((size_t)gw << 6) + (lg << 2)]);
  const float qx = bf2f(q4.x), qy = bf2f(q4.y), qz = bf2f(q4.z), qw = bf2f(q4.w);
  const ushort_t* Kbase = K + ((size_t)bh << 17);  // bh * L * D
  const int* sp = sidx + l * Uc;
  float mx = -1e30f, sm = 0.f;
#pragma unroll 4
  for (int u = 0; u < Uc; ++u) {
    const int idx = sp[u];
    const ushort4 k4 = *reinterpret_cast<const ushort4*>(&Kbase[((size_t)idx << 6) + (lg << 2)]);
    float d = qx * bf2f(k4.x) + qy * bf2f(k4.y) + qz * bf2f(k4.z) + qw * bf2f(k4.w);
#pragma unroll
    for (int off = 8; off > 0; off >>= 1) d += __shfl_xor(d, off);
    mx = fmaxf(mx, d);
    sm += d;
  }
  if (lg == 0) Mout[gw] = mx - sm * (1.f / Uc);
}

// ---------------------------------------------------------------------------
// Exact top-k via threshold screen: block per bh. Binary-search the 40th
// largest (sortable-uint domain), then exact rank-count the ~40 survivors.
// ---------------------------------------------------------------------------
__global__ __launch_bounds__(256) void topk_kernel(const float* __restrict__ Min,
                                                   int* __restrict__ Mtop) {
  __shared__ unsigned sm[Lc];   // sortable-uint copies
  __shared__ int scount[4];
  __shared__ int slist[Lc];
  __shared__ int snum;
  const int bh = blockIdx.x;
  const int tid = threadIdx.x;
  const int wv = tid >> 6, lane = tid & 63;
  unsigned sv[8];
#pragma unroll
  for (int t = 0; t < 8; ++t) {
    const unsigned u = __float_as_uint(Min[bh * Lc + tid + (t << 8)]);
    const unsigned s = (u & 0x80000000u) ? ~u : (u | 0x80000000u);
    sv[t] = s;
    sm[tid + (t << 8)] = s;
  }
  if (tid == 0) snum = 0;
  __syncthreads();
  // binary search: largest thr with count(sv >= thr) >= Uc  (== 40th largest)
  unsigned lo = 0u, hi = 0xFFFFFFFFu;
  while (lo < hi) {
    const unsigned mid =
        (unsigned)(((unsigned long long)lo + (unsigned long long)hi + 1ull) >> 1);
    int cnt = 0;
#pragma unroll
    for (int t = 0; t < 8; ++t) cnt += (sv[t] >= mid);
#pragma unroll
    for (int off = 32; off > 0; off >>= 1) cnt += __shfl_xor(cnt, off);
    if (lane == 0) scount[wv] = cnt;
    __syncthreads();
    const int total = scount[0] + scount[1] + scount[2] + scount[3];
    __syncthreads();
    if (total >= Uc) lo = mid; else hi = mid - 1;
  }
  // collect survivors (every rank<Uc candidate has sv >= lo)
#pragma unroll
  for (int t = 0; t < 8; ++t)
    if (sv[t] >= lo) {
      const int pos = atomicAdd(&snum, 1);
      slist[pos] = tid + (t << 8);
    }
  __syncthreads();
  // exact rank for each survivor; wave-cooperative scan (lane covers 32 elems)
  const int S = snum;
  const int jbase = lane << 5;
  for (int s = wv; s < S; s += 4) {
    const int c = slist[s];
    const unsigned mv = sm[c];
    int rank = 0;
#pragma unroll
    for (int q = 0; q < 8; ++q) {
      const int j = jbase + (q << 2);
      const uint4 w4 = *reinterpret_cast<const uint4*>(&sm[j]);
      rank += (w4.x > mv || (w4.x == mv && (j + 0) < c));
      rank += (w4.y > mv || (w4.y == mv && (j + 1) < c));
      rank += (w4.z > mv || (w4.z == mv && (j + 2) < c));
      rank += (w4.w > mv || (w4.w == mv && (j + 3) < c));
    }
#pragma unroll
    for (int off = 32; off > 0; off >>= 1) rank += __shfl_xor(rank, off);
    if (lane == 0 && rank < Uc) Mtop[bh * Uc + rank] = c;
  }
}

// ---------------------------------------------------------------------------
// MFMA flash attention: block = (bh, chunk of 128 keys). bf16 K/V read ONCE.
// ---------------------------------------------------------------------------
__global__ __launch_bounds__(256, 3) void attn_flash(
    const ushort_t* __restrict__ Q, const ushort_t* __restrict__ K,
    const ushort_t* __restrict__ V, const int* __restrict__ Mtop,
    float* __restrict__ m_p, float* __restrict__ l_p, float* __restrict__ o_p) {
  __shared__ __align__(16) ushort_t Qs[48 * 80];    // 7680 B, row stride 80
  __shared__ __align__(16) ushort_t KVs[128 * 80];  // 20480 B; Vt[64][144] overlays
  __shared__ __align__(16) ushort_t Ps[48 * 144];   // 13824 B, row stride 144
  __shared__ float mw[4][48];
  __shared__ float lw[4][48];
  const int tid = threadIdx.x;
  const int lane = tid & 63, w = tid >> 6;
  const int cc = lane & 15, hi = lane >> 4;
  const int bh = blockIdx.x >> 4, chunk = blockIdx.x & 15;
  const int kk0 = chunk << 7;
  const ushort_t* Qb = Q + ((size_t)bh << 17);
  const ushort_t* Kb = K + ((size_t)bh << 17);
  const ushort_t* Vb = V + ((size_t)bh << 17);

  // stage Qs (gathered selected rows; rows >= Uc zeroed) and Ks
  for (int i = tid; i < 48 * 8; i += 256) {
    const int r = i >> 3, c8 = (i & 7) << 3;
    bf16x8 v = 0;
    if (r < Uc) {
      const int lsel = Mtop[bh * Uc + r];
      v = *reinterpret_cast<const bf16x8*>(&Qb[((size_t)lsel << 6) + c8]);
    }
    *reinterpret_cast<bf16x8*>(&Qs[r * 80 + c8]) = v;
  }
  for (int i = tid; i < 128 * 8; i += 256) {
    const int r = i >> 3, c8 = (i & 7) << 3;
    *reinterpret_cast<bf16x8*>(&KVs[r * 80 + c8]) =
        *reinterpret_cast<const bf16x8*>(&Kb[((size_t)(kk0 + r) << 6) + c8]);
  }
  __syncthreads();

  // S slice: wave w covers cols [w*32, w*32+32), K-dim 64 = 2 ksteps
  f32x4 sacc[3][2] = {};
#pragma unroll
  for (int s = 0; s < 2; ++s) {
    bf16x8 af[3], bk[2];
#pragma unroll
    for (int i = 0; i < 3; ++i)
      af[i] = *reinterpret_cast<const bf16x8*>(&Qs[(i * 16 + cc) * 80 + s * 32 + hi * 8]);
#pragma unroll
    for (int jj = 0; jj < 2; ++jj)
      bk[jj] = *reinterpret_cast<const bf16x8*>(&KVs[(w * 32 + jj * 16 + cc) * 80 + s * 32 + hi * 8]);
#pragma unroll
    for (int i = 0; i < 3; ++i)
#pragma unroll
      for (int jj = 0; jj < 2; ++jj)
        sacc[i][jj] = __builtin_amdgcn_mfma_f32_16x16x32_bf16(af[i], bk[jj], sacc[i][jj], 0, 0, 0);
  }

  // per-wave row max (scaled)
  float mx[3][4];
#pragma unroll
  for (int i = 0; i < 3; ++i)
#pragma unroll
    for (int r = 0; r < 4; ++r)
      mx[i][r] = fmaxf(sacc[i][0][r], sacc[i][1][r]) * 0.125f;
#pragma unroll
  for (int off = 1; off < 16; off <<= 1)
#pragma unroll
    for (int i = 0; i < 3; ++i)
#pragma unroll
      for (int r = 0; r < 4; ++r)
        mx[i][r] = fmaxf(mx[i][r], __shfl_xor(mx[i][r], off));
  if (cc == 0)
#pragma unroll
    for (int i = 0; i < 3; ++i)
#pragma unroll
      for (int r = 0; r < 4; ++r) mw[w][i * 16 + (hi << 2) + r] = mx[i][r];
  __syncthreads();  // also: all MFMA reads of KVs done -> Vt overlay safe

  // final chunk max; p = exp(s*scale - m); Ps bf16; l partials
  float fm[3][4], ls[3][4];
#pragma unroll
  for (int i = 0; i < 3; ++i)
#pragma unroll
    for (int r = 0; r < 4; ++r) {
      const int row = i * 16 + (hi << 2) + r;
      fm[i][r] = fmaxf(fmaxf(mw[0][row], mw[1][row]), fmaxf(mw[2][row], mw[3][row]));
      ls[i][r] = 0.f;
    }
#pragma unroll
  for (int i = 0; i < 3; ++i)
#pragma unroll
    for (int jj = 0; jj < 2; ++jj)
#pragma unroll
      for (int r = 0; r < 4; ++r) {
        float p = __expf(sacc[i][jj][r] * 0.125f - fm[i][r]);
        ls[i][r] += p;
        Ps[(i * 16 + (hi << 2) + r) * 144 + w * 32 + jj * 16 + cc] = f2bf(p);
      }
#pragma unroll
  for (int off = 1; off < 16; off <<= 1)
#pragma unroll
    for (int i = 0; i < 3; ++i)
#pragma unroll
      for (int r = 0; r < 4; ++r) ls[i][r] += __shfl_xor(ls[i][r], off);
  if (cc == 0)
#pragma unroll
    for (int i = 0; i < 3; ++i)
#pragma unroll
      for (int r = 0; r < 4; ++r) lw[w][i * 16 + (hi << 2) + r] = ls[i][r];

  // stage V transposed over dead K: Vt[d][k], row stride 144 bf16
  {
    ushort_t* Vt = KVs;
    for (int i = tid; i < 128 * 8; i += 256) {
      const int k = i >> 3, c8 = (i & 7) << 3;
      bf16x8 v = *reinterpret_cast<const bf16x8*>(&Vb[((size_t)(kk0 + k) << 6) + c8]);
#pragma unroll
      for (int jq = 0; jq < 8; ++jq) Vt[(c8 + jq) * 144 + k] = (ushort_t)v[jq];
    }
  }
  __syncthreads();

  // PV: wave w covers out cols [w*16, w*16+16); K-dim 128 = 4 ksteps
  f32x4 oacc[3] = {};
#pragma unroll
  for (int s = 0; s < 4; ++s) {
    bf16x8 ap[3], bv;
#pragma unroll
    for (int i = 0; i < 3; ++i)
      ap[i] = *reinterpret_cast<const bf16x8*>(&Ps[(i * 16 + cc) * 144 + s * 32 + hi * 8]);
    bv = *reinterpret_cast<const bf16x8*>(&KVs[(w * 16 + cc) * 144 + s * 32 + hi * 8]);
#pragma unroll
    for (int i = 0; i < 3; ++i)
      oacc[i] = __builtin_amdgcn_mfma_f32_16x16x32_bf16(ap[i], bv, oacc[i], 0, 0, 0);
  }
#pragma unroll
  for (int i = 0; i < 3; ++i)
#pragma unroll
    for (int r = 0; r < 4; ++r) {
      const int row = i * 16 + (hi << 2) + r;
      if (row < Uc)
        o_p[((size_t)((bh * Uc + row) * 16 + chunk) << 6) + w * 16 + cc] = oacc[i][r];
    }
  if (w == 0 && cc == 0)
#pragma unroll
    for (int i = 0; i < 3; ++i)
#pragma unroll
      for (int r = 0; r < 4; ++r) {
        const int row = i * 16 + (hi << 2) + r;
        if (row < Uc) {
          m_p[(bh * Uc + row) * 16 + chunk] = fm[i][r];
          l_p[(bh * Uc + row) * 16 + chunk] =
              lw[0][row] + lw[1][row] + lw[2][row] + lw[3][row];
        }
      }
}

// merge 16 chunk partials; write bf16 ctx into CTXb at selected rows
__global__ __launch_bounds__(256) void attn_combine(
    const float* __restrict__ m_p, const float* __restrict__ l_p,
    const float* __restrict__ o_p, const int* __restrict__ Mtop,
    ushort_t* __restrict__ ctxb) {
  const int w = (blockIdx.x * 256 + threadIdx.x) >> 6;  // bh*40+u
  const int lane = threadIdx.x & 63;
  const float* mp = m_p + w * 16;
  const float* lp = l_p + w * 16;
  float M = -1e30f;
#pragma unroll
  for (int c = 0; c < 16; ++c) M = fmaxf(M, mp[c]);
  float denom = 0.f;
  float wgt[16];
#pragma unroll
  for (int c = 0; c < 16; ++c) {
    wgt[c] = __expf(mp[c] - M);
    denom += lp[c] * wgt[c];
  }
  float acc = 0.f;
#pragma unroll
  for (int c = 0; c < 16; ++c)
    acc += o_p[((size_t)w * 16 + c) * 64 + lane] * wgt[c];
  const int bh = w / Uc;
  const int b = bh >> 3, h = bh & 7;
  const int lsel = Mtop[w];
  ctxb[(size_t)(b * Lc + lsel) * DMc + (h << 6) + lane] = f2bf(acc / denom);
}

__global__ __launch_bounds__(64) void vmean_kernel(const ushort_t* __restrict__ V,
                                                   float* __restrict__ vmean) {
  int blk = blockIdx.x;  // B*H*8
  int bh = blk >> 3, c = blk & 7;
  int lane = threadIdx.x;
  float sm = 0.f;
  int lbase = c << 8;
  for (int l = lbase; l < lbase + 256; ++l)
    sm += bf2f(V[((size_t)(bh * Lc + l) << 6) + lane]);
  atomicAdd(&vmean[(bh << 6) + lane], sm * (1.f / Lc));
}

// ctxb[b,l,h*64+d] = bf16(vmean[b*512 + (h*64+d)])
__global__ __launch_bounds__(256) void build_ctx_kernel(const float* __restrict__ vmean,
                                                        ushort_t* __restrict__ ctxb) {
  int idx = blockIdx.x * 256 + threadIdx.x;
  ctxb[idx] = f2bf(vmean[((idx >> 20) << 9) + (idx & 511)]);
}

// out = LayerNorm(resid + yin [+ yin2]) * g + b ; optional bf16 copy. In-place safe.
__global__ __launch_bounds__(256) void add_ln_kernel(
    const float* __restrict__ resid, const float* __restrict__ yin,
    const float* __restrict__ yin2, const float* __restrict__ g,
    const float* __restrict__ bbias, float* __restrict__ out,
    ushort_t* __restrict__ outb) {
  __shared__ float vals[DMc];
  __shared__ float red[4];
  int row = blockIdx.x, tid = threadIdx.x;
  size_t base = (size_t)row * DMc;
  float lsum = 0.f;
  for (int c = tid; c < DMc; c += 256) {
    float t = resid[base + c] + yin[base + c];
    if (yin2) t += yin2[base + c];
    vals[c] = t;
    lsum += t;
  }
  lsum = wave_sum(lsum);
  if ((tid & 63) == 0) red[tid >> 6] = lsum;
  __syncthreads();
  float mean = (red[0] + red[1] + red[2] + red[3]) * (1.f / DMc);
  __syncthreads();
  float lv = 0.f;
  for (int c = tid; c < DMc; c += 256) {
    float dv = vals[c] - mean;
    lv += dv * dv;
  }
  lv = wave_sum(lv);
  if ((tid & 63) == 0) red[tid >> 6] = lv;
  __syncthreads();
  float inv = rsqrtf((red[0] + red[1] + red[2] + red[3]) * (1.f / DMc) + 1e-5f);
  for (int c = tid; c < DMc; c += 256) {
    float o = (vals[c] - mean) * inv * g[c] + bbias[c];
    out[base + c] = o;
    if (outb) outb[base + c] = f2bf(o);
  }
}

extern "C" void kernel_launch(void* const* d_in, const int* in_sizes, int n_in,
                              void* d_out, int out_size, void* d_ws, size_t ws_size,
                              hipStream_t stream) {
  (void)in_sizes; (void)n_in; (void)out_size; (void)ws_size;
  const float* x   = (const float*)d_in[0];
  const float* Wq  = (const float*)d_in[1];
  const float* bq  = (const float*)d_in[2];
  const float* Wk  = (const float*)d_in[3];
  const float* bk  = (const float*)d_in[4];
  const float* Wv  = (const float*)d_in[5];
  const float* bv  = (const float*)d_in[6];
  const float* Wo  = (const float*)d_in[7];
  const float* bo  = (const float*)d_in[8];
  const float* Wc1 = (const float*)d_in[9];
  const float* bc1 = (const float*)d_in[10];
  const float* Wc2 = (const float*)d_in[11];
  const float* bc2 = (const float*)d_in[12];
  const float* g1  = (const float*)d_in[13];
  const float* b1  = (const float*)d_in[14];
  const float* g2  = (const float*)d_in[15];
  const float* b2  = (const float*)d_in[16];
  const int* sidx  = (const int*)d_in[17];
  float* out = (float*)d_out;

  float* ws = (float*)d_ws;
  // f32-word offsets (Q/K/V bf16, each 2M words used of their 4M slots)
  ushort_t* Qb   = (ushort_t*)ws;               // bf16 (B,H,L,D) 8MB
  ushort_t* Kb   = (ushort_t*)(ws + 4194304);   // bf16 8MB
  ushort_t* Vb   = (ushort_t*)(ws + 8388608);   // bf16 8MB
  // ws+12582912 .. +16777216: attn partials (early) / X1b bf16 (late)
  float* m_p    = ws + 12582912;            // 20480
  float* l_p    = ws + 12603392;            // 20480
  float* o_p    = ws + 12623872;            // 1,310,720
  float* X1     = ws + 16777216;            // 4M
  ushort_t* xb   = (ushort_t*)(ws + 20971520);  // [8192][512] bf16 (2M words)
  ushort_t* Wqkvt= (ushort_t*)(ws + 23068672);  // [1536][512] bf16
  ushort_t* Wot  = (ushort_t*)(ws + 23461888);  // [512][512] bf16
  ushort_t* Wc1b = (ushort_t*)(ws + 23592960);  // [2048][512] bf16
  ushort_t* Wc2b = (ushort_t*)(ws + 24117248);  // [512][2048] bf16
  float* bqkv   = ws + 24641536;            // 1536
  float* Mb     = ws + 24643072;            // 65536
  float* vmean  = ws + 24708608;            // 2048
  int* Mtop     = (int*)(ws + 24710656);    // 1280
  // aliases (producer runs strictly after last consumer of the dead buffer)
  ushort_t* CTXb = Vb;                          // bf16 [8192][512], after vmean
  ushort_t* X1b  = (ushort_t*)(ws + 12582912);  // bf16 [8192][512], after combine
  ushort_t* Yb   = (ushort_t*)ws;               // bf16 [8192][2048] = Qb+Kb slots, after attn
  float* woP1   = ws + 4194304;             // f32 [8192][512] over Kb slot, after attn
  float* ffP1   = ws + 8388608;             // f32 [8192][512] over Vb slot, after Wo

  dim3 blk(256);
  prep_kernel<<<7174, blk, 0, stream>>>(x, Wq, Wk, Wv, Wo, Wc1, Wc2, bq, bk, bv,
                                        xb, Wqkvt, Wot, Wc1b, Wc2b, bqkv);

  gemm_mfma<2><<<dim3(12, 64), blk, 0, stream>>>(xb, Wqkvt, bqkv, nullptr, nullptr,
                                                 nullptr, Qb, Kb, Vb, NT, 1536, DMc, DMc);
  compute_M_kernel<<<4096, blk, 0, stream>>>(Qb, Kb, sidx, Mb);
  topk_kernel<<<32, blk, 0, stream>>>(Mb, Mtop);
  attn_flash<<<512, blk, 0, stream>>>(Qb, Kb, Vb, Mtop, m_p, l_p, o_p);
  hipMemsetAsync(vmean, 0, Bc * Hc * Dc * sizeof(float), stream);
  vmean_kernel<<<Bc * Hc * 8, dim3(64), 0, stream>>>(Vb, vmean);
  build_ctx_kernel<<<16384, blk, 0, stream>>>(vmean, CTXb);
  attn_combine<<<320, blk, 0, stream>>>(m_p, l_p, o_p, Mtop, CTXb);

  // Wo: split-K=2 -> out (+bias) and woP1
  gemm_mfma<3><<<dim3(4, 128), blk, 0, stream>>>(CTXb, Wot, bo, out, woP1,
                                                 nullptr, nullptr, nullptr, nullptr,
                                                 NT, DMc, DMc, DMc / 2);
  add_ln_kernel<<<NT, blk, 0, stream>>>(x, out, woP1, g1, b1, X1, X1b);
  gemm_mfma<1><<<dim3(16, 64), blk, 0, stream>>>(X1b, Wc1b, bc1, nullptr, nullptr,
                                                 Yb, nullptr, nullptr, nullptr,
                                                 NT, DFFc, DMc, DMc);
  // FFN2: split-K=2 -> out (+bias) and ffP1
  gemm_mfma<3><<<dim3(4, 128), blk, 0, stream>>>(Yb, Wc2b, bc2, out, ffP1,
                                                 nullptr, nullptr, nullptr, nullptr,
                                                 NT, DMc, DFFc, DFFc / 2);
  add_ln_kernel<<<NT, blk, 0, stream>>>(X1, out, ffP1, g2, b2, out, nullptr);
}